// Round 2
// baseline (1064.873 us; speedup 1.0000x reference)
//
#include <hip/hip_runtime.h>

typedef unsigned short u16;
typedef unsigned int u32;
typedef __attribute__((ext_vector_type(8))) short bf16x8;
typedef __attribute__((ext_vector_type(4))) float f32x4;

#define LSEQ 1024

__device__ __forceinline__ float b2f(u16 v) { return __uint_as_float(((u32)v) << 16); }
__device__ __forceinline__ u16 f2b(float f) {
    u32 x = __float_as_uint(f);
    return (u16)((x + 0x7fffu + ((x >> 16) & 1u)) >> 16);
}
// dual-dtype scalar read: f=1 -> bf16, f=0 -> fp32
__device__ __forceinline__ float rdf(const void* p, int i, int f) {
    return f ? b2f(((const u16*)p)[i]) : ((const float*)p)[i];
}

// ---------------- dtype detection: sample first 2048 u16 halves of x ----------------
__global__ void detect_k(const u16* __restrict__ x, int* __restrict__ flag) {
    __shared__ int cnt;
    if (threadIdx.x == 0) cnt = 0;
    __syncthreads();
    int c = 0;
#pragma unroll
    for (int j = 0; j < 8; ++j) {
        u16 u = x[threadIdx.x * 8 + j];
        int e = (u >> 7) & 0xFF;
        c += (e == 0 || (e >= 100 && e <= 140)) ? 1 : 0;
    }
    atomicAdd(&cnt, c);
    __syncthreads();
    if (threadIdx.x == 0) *flag = (cnt >= 1638) ? 1 : 0;  // >=80% plausible -> bf16
}

// ---------------- canonicalize input tensor to bf16 ----------------
__global__ __launch_bounds__(256) void cvt_k(const void* __restrict__ src,
                                             u16* __restrict__ dst, int n,
                                             const int* __restrict__ flag) {
    int f = *flag;
    int i = blockIdx.x * 256 + threadIdx.x;
    if (i >= n) return;
    dst[i] = f ? ((const u16*)src)[i] : f2b(((const float*)src)[i]);
}

// ---------------- GEMM: C[M,N] = A[M,K]*B[K,N], bf16 in, fp32 acc ----------------
// OUT_MODE: 0=fp32, 1=bf16, 2=dual(flag)
template <int OUT_MODE>
__global__ __launch_bounds__(256) void gemm_k(const u16* __restrict__ A,
                                              const u16* __restrict__ B,
                                              void* __restrict__ C,
                                              int M, int N, int K,
                                              const int* __restrict__ flag) {
    __shared__ __align__(16) u16 As[64 * 56];
    __shared__ __align__(16) u16 Bs[64 * 56];
    const int tid = threadIdx.x;
    const int wid = tid >> 6, lane = tid & 63;
    const int wm = wid & 1, wn = wid >> 1;
    const int m_blk = blockIdx.x * 64, n_blk = blockIdx.y * 64;
    const int lm = lane & 15, lq = lane >> 4;
    const int ar = tid >> 2, ac = (tid & 3) << 3;
    const int bn = tid & 63, bk = (tid >> 6) << 3;
    const int gn = n_blk + bn;
    const int f = (OUT_MODE == 2) ? flag[0] : 0;

    f32x4 zero = {0.f, 0.f, 0.f, 0.f};
    f32x4 acc[2][2];
    acc[0][0] = zero; acc[0][1] = zero; acc[1][0] = zero; acc[1][1] = zero;

    for (int kb = 0; kb < K; kb += 32) {
        bf16x8 av = *(const bf16x8*)(A + (size_t)(m_blk + ar) * K + kb + ac);
        short bv[8];
        if (gn < N) {
#pragma unroll
            for (int j = 0; j < 8; ++j) bv[j] = (short)B[(size_t)(kb + bk + j) * N + gn];
        } else {
#pragma unroll
            for (int j = 0; j < 8; ++j) bv[j] = 0;
        }
        __syncthreads();
        *(bf16x8*)(As + ar * 56 + ac) = av;
        bf16x8 bvv;
#pragma unroll
        for (int j = 0; j < 8; ++j) bvv[j] = bv[j];
        *(bf16x8*)(Bs + bn * 56 + bk) = bvv;
        __syncthreads();

        bf16x8 af0 = *(const bf16x8*)(As + (wm * 32 + lm) * 56 + lq * 8);
        bf16x8 af1 = *(const bf16x8*)(As + (wm * 32 + 16 + lm) * 56 + lq * 8);
        bf16x8 bf0 = *(const bf16x8*)(Bs + (wn * 32 + lm) * 56 + lq * 8);
        bf16x8 bf1 = *(const bf16x8*)(Bs + (wn * 32 + 16 + lm) * 56 + lq * 8);
        acc[0][0] = __builtin_amdgcn_mfma_f32_16x16x32_bf16(af0, bf0, acc[0][0], 0, 0, 0);
        acc[0][1] = __builtin_amdgcn_mfma_f32_16x16x32_bf16(af0, bf1, acc[0][1], 0, 0, 0);
        acc[1][0] = __builtin_amdgcn_mfma_f32_16x16x32_bf16(af1, bf0, acc[1][0], 0, 0, 0);
        acc[1][1] = __builtin_amdgcn_mfma_f32_16x16x32_bf16(af1, bf1, acc[1][1], 0, 0, 0);
    }

#pragma unroll
    for (int tm = 0; tm < 2; ++tm)
#pragma unroll
        for (int tn = 0; tn < 2; ++tn)
#pragma unroll
            for (int r = 0; r < 4; ++r) {
                int row = m_blk + wm * 32 + tm * 16 + lq * 4 + r;
                int col = n_blk + wn * 32 + tn * 16 + lm;
                if (col < N) {
                    float v = acc[tm][tn][r];
                    if (OUT_MODE == 0) ((float*)C)[(size_t)row * N + col] = v;
                    else if (OUT_MODE == 1) ((u16*)C)[(size_t)row * N + col] = f2b(v);
                    else {
                        if (f) ((u16*)C)[(size_t)row * N + col] = f2b(v);
                        else   ((float*)C)[(size_t)row * N + col] = v;
                    }
                }
            }
}

// ---------------- causal depthwise conv (K=4) + SiLU ----------------
__global__ __launch_bounds__(256) void conv_silu_k(const u16* __restrict__ xz,
                                                   const void* __restrict__ cw,
                                                   const void* __restrict__ cb,
                                                   u16* __restrict__ xc,
                                                   const int* __restrict__ flag) {
    int f = *flag;
    int idx = blockIdx.x * 256 + threadIdx.x;  // over 1024*2048
    int t = idx >> 11, d = idx & 2047;
    float acc = rdf(cb, d, f);
#pragma unroll
    for (int k = 0; k < 4; ++k) {
        int tt = t + k - 3;
        if (tt >= 0) acc += b2f(xz[(size_t)tt * 4096 + d]) * rdf(cw, d * 4 + k, f);
    }
    float s = acc / (1.f + expf(-acc));
    xc[idx] = f2b(s);
}

// ---------------- extract dt columns as bf16 ----------------
__global__ __launch_bounds__(256) void dt_cvt_k(const float* __restrict__ xdbl,
                                                u16* __restrict__ dtb) {
    int idx = blockIdx.x * 256 + threadIdx.x;  // over 1024*64
    int t = idx >> 6, r = idx & 63;
    dtb[idx] = f2b(xdbl[t * 96 + r]);
}

// ---------------- softplus(raw + b_dt) in place (fp32) ----------------
__global__ __launch_bounds__(256) void softplus_k(float* __restrict__ delta,
                                                  const void* __restrict__ b_dt,
                                                  const int* __restrict__ flag) {
    int f = *flag;
    int idx = blockIdx.x * 256 + threadIdx.x;  // over 1024*2048
    int d = idx & 2047;
    float v = delta[idx] + rdf(b_dt, d, f);
    delta[idx] = fmaxf(v, 0.f) + log1pf(expf(-fabsf(v)));
}

// ---------------- selective scan: one lane per (d,n), shuffle-reduce over n ----------------
__global__ __launch_bounds__(256) void scan_k(const float* __restrict__ delta,
                                              const u16* __restrict__ xc,
                                              const float* __restrict__ xdbl,
                                              const u16* __restrict__ xz,
                                              const void* __restrict__ A_log,
                                              const void* __restrict__ Dvp,
                                              u16* __restrict__ yg,
                                              const int* __restrict__ flag) {
    int f = *flag;
    int g = blockIdx.x * 256 + threadIdx.x;  // over 2048*16
    int d = g >> 4, n = g & 15;
    float A = -expf(rdf(A_log, d * 16 + n, f));
    float Dd = rdf(Dvp, d, f);
    float h = 0.f;
    for (int t = 0; t < LSEQ; ++t) {
        float de = delta[t * 2048 + d];
        float u = b2f(xc[t * 2048 + d]);
        float Bv = xdbl[t * 96 + 64 + n];
        float Cv = xdbl[t * 96 + 80 + n];
        h = expf(de * A) * h + (de * Bv) * u;
        float p = h * Cv;
        p += __shfl_xor(p, 1);
        p += __shfl_xor(p, 2);
        p += __shfl_xor(p, 4);
        p += __shfl_xor(p, 8);
        if (n == 0) {
            float r = b2f(xz[(size_t)t * 4096 + 2048 + d]);
            float yt = p + u * Dd;
            float gv = yt * (r / (1.f + expf(-r)));
            yg[t * 2048 + d] = f2b(gv);
        }
    }
}

extern "C" void kernel_launch(void* const* d_in, const int* in_sizes, int n_in,
                              void* d_out, int out_size, void* d_ws, size_t ws_size,
                              hipStream_t stream) {
    const void* x      = d_in[0];  // [1024,1024]
    const void* W_in   = d_in[1];  // [1024,4096]
    const void* conv_w = d_in[2];  // [2048,4]
    const void* conv_b = d_in[3];  // [2048]
    const void* W_x    = d_in[4];  // [2048,96]
    const void* W_dt   = d_in[5];  // [64,2048]
    const void* b_dt   = d_in[6];  // [2048]
    const void* A_log  = d_in[7];  // [2048,16]
    const void* Dv     = d_in[8];  // [2048]
    const void* W_out  = d_in[9];  // [2048,1024]

    char* ws = (char*)d_ws;
    u16*   xz     = (u16*)(ws);               // 8388608 B
    u16*   xconv  = (u16*)(ws + 8388608);     // 4194304 B
    float* xdbl   = (float*)(ws + 12582912);  // 393216 B
    u16*   dtb    = (u16*)(ws + 12976128);    // 131072 B
    float* delta  = (float*)(ws + 13107200);  // 8388608 B (also aliases W_in_b before step 5)
    u16*   W_in_b = (u16*)(ws + 13107200);    // alias: used only in GEMM1 (before delta written)
    u16*   yg     = (u16*)(ws + 21495808);    // 4194304 B (also aliases xb before scan)
    u16*   xb     = (u16*)(ws + 21495808);    // alias: used only in GEMM1 (before yg written)
    u16*   W_x_b  = (u16*)(ws + 25690112);    // 393216 B
    u16*   W_dt_b = (u16*)(ws + 26083328);    // 262144 B
    u16*   W_out_b= (u16*)(ws + 26345472);    // 4194304 B
    int*   flag   = (int*)(ws + 30539776);    // 4 B   (total ~30.5 MB)

    // 0) dtype detect
    detect_k<<<1, 256, 0, stream>>>((const u16*)x, flag);
    // 0b) canonicalize big tensors to bf16
    cvt_k<<<4096, 256, 0, stream>>>(x, xb, 1048576, flag);
    cvt_k<<<16384, 256, 0, stream>>>(W_in, W_in_b, 4194304, flag);
    cvt_k<<<768, 256, 0, stream>>>(W_x, W_x_b, 196608, flag);
    cvt_k<<<512, 256, 0, stream>>>(W_dt, W_dt_b, 131072, flag);
    cvt_k<<<8192, 256, 0, stream>>>(W_out, W_out_b, 2097152, flag);

    // 1) xz = x @ W_in   [1024,4096] bf16
    gemm_k<1><<<dim3(16, 64), 256, 0, stream>>>(xb, W_in_b, (void*)xz, 1024, 4096, 1024, flag);
    // 2) x_conv = silu(causal_dw_conv(x_in))
    conv_silu_k<<<8192, 256, 0, stream>>>(xz, conv_w, conv_b, xconv, flag);
    // 3) x_dbl = x_conv @ W_x   [1024,96] fp32
    gemm_k<0><<<dim3(16, 2), 256, 0, stream>>>(xconv, W_x_b, (void*)xdbl, 1024, 96, 2048, flag);
    // 4) dt -> bf16
    dt_cvt_k<<<256, 256, 0, stream>>>(xdbl, dtb);
    // 5) delta_raw = dt @ W_dt   [1024,2048] fp32, then softplus(+b_dt)
    gemm_k<0><<<dim3(16, 32), 256, 0, stream>>>(dtb, W_dt_b, (void*)delta, 1024, 2048, 64, flag);
    softplus_k<<<8192, 256, 0, stream>>>(delta, b_dt, flag);
    // 6) selective scan + gating -> yg bf16
    scan_k<<<128, 256, 0, stream>>>(delta, xconv, xdbl, xz, A_log, Dv, yg, flag);
    // 7) out = yg @ W_out   [1024,1024], dtype per flag
    gemm_k<2><<<dim3(16, 16), 256, 0, stream>>>(yg, W_out_b, d_out, 1024, 1024, 2048, flag);
}

// Round 3
// 338.187 us; speedup vs baseline: 3.1488x; 3.1488x over previous
//
#include <hip/hip_runtime.h>

typedef unsigned short u16;
typedef unsigned int u32;
typedef __attribute__((ext_vector_type(8))) short bf16x8;
typedef __attribute__((ext_vector_type(4))) float f32x4;

#define LSEQ 1024

__device__ __forceinline__ float b2f(u16 v) { return __uint_as_float(((u32)v) << 16); }
__device__ __forceinline__ u16 f2b(float f) {
    u32 x = __float_as_uint(f);
    return (u16)((x + 0x7fffu + ((x >> 16) & 1u)) >> 16);
}
// dual-dtype scalar read: f=1 -> bf16, f=0 -> fp32
__device__ __forceinline__ float rdf(const void* p, int i, int f) {
    return f ? b2f(((const u16*)p)[i]) : ((const float*)p)[i];
}

// ---------------- dtype detection: sample first 2048 u16 halves of x ----------------
__global__ void detect_k(const u16* __restrict__ x, int* __restrict__ flag) {
    __shared__ int cnt;
    if (threadIdx.x == 0) cnt = 0;
    __syncthreads();
    int c = 0;
#pragma unroll
    for (int j = 0; j < 8; ++j) {
        u16 u = x[threadIdx.x * 8 + j];
        int e = (u >> 7) & 0xFF;
        c += (e == 0 || (e >= 100 && e <= 140)) ? 1 : 0;
    }
    atomicAdd(&cnt, c);
    __syncthreads();
    if (threadIdx.x == 0) *flag = (cnt >= 1638) ? 1 : 0;  // >=80% plausible -> bf16
}

// ---------------- canonicalize input tensor to bf16 ----------------
__global__ __launch_bounds__(256) void cvt_k(const void* __restrict__ src,
                                             u16* __restrict__ dst, int n,
                                             const int* __restrict__ flag) {
    int f = *flag;
    int i = blockIdx.x * 256 + threadIdx.x;
    if (i >= n) return;
    dst[i] = f ? ((const u16*)src)[i] : f2b(((const float*)src)[i]);
}

// ---------------- GEMM: C[M,N] = A[M,K]*B[K,N], bf16 in, fp32 acc ----------------
// OUT_MODE: 0=fp32, 1=bf16, 2=dual(flag)
template <int OUT_MODE>
__global__ __launch_bounds__(256) void gemm_k(const u16* __restrict__ A,
                                              const u16* __restrict__ B,
                                              void* __restrict__ C,
                                              int M, int N, int K,
                                              const int* __restrict__ flag) {
    __shared__ __align__(16) u16 As[64 * 56];
    __shared__ __align__(16) u16 Bs[64 * 56];
    const int tid = threadIdx.x;
    const int wid = tid >> 6, lane = tid & 63;
    const int wm = wid & 1, wn = wid >> 1;
    const int m_blk = blockIdx.x * 64, n_blk = blockIdx.y * 64;
    const int lm = lane & 15, lq = lane >> 4;
    const int ar = tid >> 2, ac = (tid & 3) << 3;
    const int bn = tid & 63, bk = (tid >> 6) << 3;
    const int gn = n_blk + bn;
    const int f = (OUT_MODE == 2) ? flag[0] : 0;

    f32x4 zero = {0.f, 0.f, 0.f, 0.f};
    f32x4 acc[2][2];
    acc[0][0] = zero; acc[0][1] = zero; acc[1][0] = zero; acc[1][1] = zero;

    for (int kb = 0; kb < K; kb += 32) {
        bf16x8 av = *(const bf16x8*)(A + (size_t)(m_blk + ar) * K + kb + ac);
        short bv[8];
        if (gn < N) {
#pragma unroll
            for (int j = 0; j < 8; ++j) bv[j] = (short)B[(size_t)(kb + bk + j) * N + gn];
        } else {
#pragma unroll
            for (int j = 0; j < 8; ++j) bv[j] = 0;
        }
        __syncthreads();
        *(bf16x8*)(As + ar * 56 + ac) = av;
        bf16x8 bvv;
#pragma unroll
        for (int j = 0; j < 8; ++j) bvv[j] = bv[j];
        *(bf16x8*)(Bs + bn * 56 + bk) = bvv;
        __syncthreads();

        bf16x8 af0 = *(const bf16x8*)(As + (wm * 32 + lm) * 56 + lq * 8);
        bf16x8 af1 = *(const bf16x8*)(As + (wm * 32 + 16 + lm) * 56 + lq * 8);
        bf16x8 bf0 = *(const bf16x8*)(Bs + (wn * 32 + lm) * 56 + lq * 8);
        bf16x8 bf1 = *(const bf16x8*)(Bs + (wn * 32 + 16 + lm) * 56 + lq * 8);
        acc[0][0] = __builtin_amdgcn_mfma_f32_16x16x32_bf16(af0, bf0, acc[0][0], 0, 0, 0);
        acc[0][1] = __builtin_amdgcn_mfma_f32_16x16x32_bf16(af0, bf1, acc[0][1], 0, 0, 0);
        acc[1][0] = __builtin_amdgcn_mfma_f32_16x16x32_bf16(af1, bf0, acc[1][0], 0, 0, 0);
        acc[1][1] = __builtin_amdgcn_mfma_f32_16x16x32_bf16(af1, bf1, acc[1][1], 0, 0, 0);
    }

#pragma unroll
    for (int tm = 0; tm < 2; ++tm)
#pragma unroll
        for (int tn = 0; tn < 2; ++tn)
#pragma unroll
            for (int r = 0; r < 4; ++r) {
                int row = m_blk + wm * 32 + tm * 16 + lq * 4 + r;
                int col = n_blk + wn * 32 + tn * 16 + lm;
                if (col < N) {
                    float v = acc[tm][tn][r];
                    if (OUT_MODE == 0) ((float*)C)[(size_t)row * N + col] = v;
                    else if (OUT_MODE == 1) ((u16*)C)[(size_t)row * N + col] = f2b(v);
                    else {
                        if (f) ((u16*)C)[(size_t)row * N + col] = f2b(v);
                        else   ((float*)C)[(size_t)row * N + col] = v;
                    }
                }
            }
}

// ---------------- causal depthwise conv (K=4) + SiLU ----------------
__global__ __launch_bounds__(256) void conv_silu_k(const u16* __restrict__ xz,
                                                   const void* __restrict__ cw,
                                                   const void* __restrict__ cb,
                                                   u16* __restrict__ xc,
                                                   const int* __restrict__ flag) {
    int f = *flag;
    int idx = blockIdx.x * 256 + threadIdx.x;  // over 1024*2048
    int t = idx >> 11, d = idx & 2047;
    float acc = rdf(cb, d, f);
#pragma unroll
    for (int k = 0; k < 4; ++k) {
        int tt = t + k - 3;
        if (tt >= 0) acc += b2f(xz[(size_t)tt * 4096 + d]) * rdf(cw, d * 4 + k, f);
    }
    float s = acc / (1.f + expf(-acc));
    xc[idx] = f2b(s);
}

// ---------------- extract dt columns as bf16 ----------------
__global__ __launch_bounds__(256) void dt_cvt_k(const float* __restrict__ xdbl,
                                                u16* __restrict__ dtb) {
    int idx = blockIdx.x * 256 + threadIdx.x;  // over 1024*64
    int t = idx >> 6, r = idx & 63;
    dtb[idx] = f2b(xdbl[t * 96 + r]);
}

// ---------------- softplus(raw + b_dt) in place (fp32) ----------------
__global__ __launch_bounds__(256) void softplus_k(float* __restrict__ delta,
                                                  const void* __restrict__ b_dt,
                                                  const int* __restrict__ flag) {
    int f = *flag;
    int idx = blockIdx.x * 256 + threadIdx.x;  // over 1024*2048
    int d = idx & 2047;
    float v = delta[idx] + rdf(b_dt, d, f);
    delta[idx] = fmaxf(v, 0.f) + log1pf(expf(-fabsf(v)));
}

// ---------------- chunked selective scan ----------------
// pass 1: per (chunk,d,n) local scan from h=0; store decay product Acar and local state Bcar
template <int T>
__global__ __launch_bounds__(256) void scan1_k(const float* __restrict__ delta,
                                               const u16* __restrict__ xc,
                                               const float* __restrict__ xdbl,
                                               const void* __restrict__ A_log,
                                               float* __restrict__ Acar,
                                               float* __restrict__ Bcar,
                                               const int* __restrict__ flag) {
    int f = *flag;
    int g = blockIdx.x * 256 + threadIdx.x;  // over C*32768
    int c = g >> 15, rem = g & 32767;
    int d = rem >> 4, n = rem & 15;
    float A = -expf(rdf(A_log, d * 16 + n, f));
    float P = 1.f, hl = 0.f;
    int t0 = c * T;
#pragma unroll 4
    for (int i = 0; i < T; ++i) {
        int t = t0 + i;
        float de = delta[t * 2048 + d];
        float u = b2f(xc[t * 2048 + d]);
        float Bv = xdbl[t * 96 + 64 + n];
        float a = expf(de * A);
        hl = a * hl + (de * Bv) * u;
        P *= a;
    }
    Acar[g] = P;
    Bcar[g] = hl;
}

// pass 2: sequential combine over chunks per (d,n); Bcar[c] <- H_c (state entering chunk c), in place
__global__ __launch_bounds__(256) void scan2_k(const float* __restrict__ Acar,
                                               float* __restrict__ Bcar, int C) {
    int idx = blockIdx.x * 256 + threadIdx.x;  // over 32768
    float H = 0.f;
    for (int c = 0; c < C; ++c) {
        float a = Acar[c * 32768 + idx];
        float b = Bcar[c * 32768 + idx];
        Bcar[c * 32768 + idx] = H;
        H = a * H + b;
    }
}

// pass 3: re-run recurrence seeded with H_c, reduce over n, gate, write yg
template <int T>
__global__ __launch_bounds__(256) void scan3_k(const float* __restrict__ delta,
                                               const u16* __restrict__ xc,
                                               const float* __restrict__ xdbl,
                                               const u16* __restrict__ xz,
                                               const void* __restrict__ A_log,
                                               const void* __restrict__ Dvp,
                                               const float* __restrict__ Bcar,
                                               u16* __restrict__ yg,
                                               const int* __restrict__ flag) {
    int f = *flag;
    int g = blockIdx.x * 256 + threadIdx.x;  // over C*32768
    int c = g >> 15, rem = g & 32767;
    int d = rem >> 4, n = rem & 15;
    float A = -expf(rdf(A_log, d * 16 + n, f));
    float Dd = rdf(Dvp, d, f);
    float h = Bcar[g];
    int t0 = c * T;
    for (int i = 0; i < T; ++i) {
        int t = t0 + i;
        float de = delta[t * 2048 + d];
        float u = b2f(xc[t * 2048 + d]);
        float Bv = xdbl[t * 96 + 64 + n];
        float Cv = xdbl[t * 96 + 80 + n];
        h = expf(de * A) * h + (de * Bv) * u;
        float p = h * Cv;
        p += __shfl_xor(p, 1);
        p += __shfl_xor(p, 2);
        p += __shfl_xor(p, 4);
        p += __shfl_xor(p, 8);
        if (n == 0) {
            float r = b2f(xz[(size_t)t * 4096 + 2048 + d]);
            float yt = p + u * Dd;
            yg[t * 2048 + d] = f2b(yt * (r / (1.f + expf(-r))));
        }
    }
}

// fallback monolithic scan (used only if ws too small for carries)
__global__ __launch_bounds__(256) void scan_k(const float* __restrict__ delta,
                                              const u16* __restrict__ xc,
                                              const float* __restrict__ xdbl,
                                              const u16* __restrict__ xz,
                                              const void* __restrict__ A_log,
                                              const void* __restrict__ Dvp,
                                              u16* __restrict__ yg,
                                              const int* __restrict__ flag) {
    int f = *flag;
    int g = blockIdx.x * 256 + threadIdx.x;
    int d = g >> 4, n = g & 15;
    float A = -expf(rdf(A_log, d * 16 + n, f));
    float Dd = rdf(Dvp, d, f);
    float h = 0.f;
    for (int t = 0; t < LSEQ; ++t) {
        float de = delta[t * 2048 + d];
        float u = b2f(xc[t * 2048 + d]);
        float Bv = xdbl[t * 96 + 64 + n];
        float Cv = xdbl[t * 96 + 80 + n];
        h = expf(de * A) * h + (de * Bv) * u;
        float p = h * Cv;
        p += __shfl_xor(p, 1);
        p += __shfl_xor(p, 2);
        p += __shfl_xor(p, 4);
        p += __shfl_xor(p, 8);
        if (n == 0) {
            float r = b2f(xz[(size_t)t * 4096 + 2048 + d]);
            float yt = p + u * Dd;
            yg[t * 2048 + d] = f2b(yt * (r / (1.f + expf(-r))));
        }
    }
}

extern "C" void kernel_launch(void* const* d_in, const int* in_sizes, int n_in,
                              void* d_out, int out_size, void* d_ws, size_t ws_size,
                              hipStream_t stream) {
    const void* x      = d_in[0];
    const void* W_in   = d_in[1];
    const void* conv_w = d_in[2];
    const void* conv_b = d_in[3];
    const void* W_x    = d_in[4];
    const void* W_dt   = d_in[5];
    const void* b_dt   = d_in[6];
    const void* A_log  = d_in[7];
    const void* Dv     = d_in[8];
    const void* W_out  = d_in[9];

    char* ws = (char*)d_ws;
    u16*   xz     = (u16*)(ws);               // 8388608 B
    u16*   xconv  = (u16*)(ws + 8388608);     // 4194304 B
    float* xdbl   = (float*)(ws + 12582912);  // 393216 B
    u16*   dtb    = (u16*)(ws + 12976128);    // 131072 B
    float* delta  = (float*)(ws + 13107200);  // 8388608 B
    u16*   W_in_b = (u16*)(ws + 13107200);    // alias: GEMM1 only (before delta written)
    u16*   yg     = (u16*)(ws + 21495808);    // 4194304 B
    u16*   xb     = (u16*)(ws + 21495808);    // alias: GEMM1 only (before yg written)
    u16*   W_x_b  = (u16*)(ws + 25690112);    // 393216 B
    u16*   W_dt_b = (u16*)(ws + 26083328);    // 262144 B
    u16*   W_out_b= (u16*)(ws + 26345472);    // 4194304 B
    int*   flag   = (int*)(ws + 30539776);    // 4 B
    float* Acar   = (float*)(ws + 30539904);  // C*131072 B
    // Bcar follows Acar, C*131072 B each

    // pick chunk count by available workspace (ws_size constant across calls -> graph-safe)
    int C = 0;
    const size_t carry_base = 30539904;
    if (carry_base + (size_t)2 * 32 * 131072 <= ws_size) C = 32;
    else if (carry_base + (size_t)2 * 16 * 131072 <= ws_size) C = 16;
    else if (carry_base + (size_t)2 * 8 * 131072 <= ws_size) C = 8;
    float* Bcar = (C > 0) ? (float*)(ws + carry_base + (size_t)C * 131072) : nullptr;

    // 0) dtype detect + canonicalize big tensors to bf16
    detect_k<<<1, 256, 0, stream>>>((const u16*)x, flag);
    cvt_k<<<4096, 256, 0, stream>>>(x, xb, 1048576, flag);
    cvt_k<<<16384, 256, 0, stream>>>(W_in, W_in_b, 4194304, flag);
    cvt_k<<<768, 256, 0, stream>>>(W_x, W_x_b, 196608, flag);
    cvt_k<<<512, 256, 0, stream>>>(W_dt, W_dt_b, 131072, flag);
    cvt_k<<<8192, 256, 0, stream>>>(W_out, W_out_b, 2097152, flag);

    // 1) xz = x @ W_in   [1024,4096] bf16
    gemm_k<1><<<dim3(16, 64), 256, 0, stream>>>(xb, W_in_b, (void*)xz, 1024, 4096, 1024, flag);
    // 2) x_conv = silu(causal_dw_conv(x_in))
    conv_silu_k<<<8192, 256, 0, stream>>>(xz, conv_w, conv_b, xconv, flag);
    // 3) x_dbl = x_conv @ W_x   [1024,96] fp32
    gemm_k<0><<<dim3(16, 2), 256, 0, stream>>>(xconv, W_x_b, (void*)xdbl, 1024, 96, 2048, flag);
    // 4) dt -> bf16
    dt_cvt_k<<<256, 256, 0, stream>>>(xdbl, dtb);
    // 5) delta_raw = dt @ W_dt   [1024,2048] fp32, then softplus(+b_dt)
    gemm_k<0><<<dim3(16, 32), 256, 0, stream>>>(dtb, W_dt_b, (void*)delta, 1024, 2048, 64, flag);
    softplus_k<<<8192, 256, 0, stream>>>(delta, b_dt, flag);

    // 6) selective scan + gating -> yg bf16 (chunked if workspace allows)
    if (C == 32) {
        scan1_k<32><<<32 * 128, 256, 0, stream>>>(delta, xconv, xdbl, A_log, Acar, Bcar, flag);
        scan2_k<<<128, 256, 0, stream>>>(Acar, Bcar, 32);
        scan3_k<32><<<32 * 128, 256, 0, stream>>>(delta, xconv, xdbl, xz, A_log, Dv, Bcar, yg, flag);
    } else if (C == 16) {
        scan1_k<64><<<16 * 128, 256, 0, stream>>>(delta, xconv, xdbl, A_log, Acar, Bcar, flag);
        scan2_k<<<128, 256, 0, stream>>>(Acar, Bcar, 16);
        scan3_k<64><<<16 * 128, 256, 0, stream>>>(delta, xconv, xdbl, xz, A_log, Dv, Bcar, yg, flag);
    } else if (C == 8) {
        scan1_k<128><<<8 * 128, 256, 0, stream>>>(delta, xconv, xdbl, A_log, Acar, Bcar, flag);
        scan2_k<<<128, 256, 0, stream>>>(Acar, Bcar, 8);
        scan3_k<128><<<8 * 128, 256, 0, stream>>>(delta, xconv, xdbl, xz, A_log, Dv, Bcar, yg, flag);
    } else {
        scan_k<<<128, 256, 0, stream>>>(delta, xconv, xdbl, xz, A_log, Dv, yg, flag);
    }

    // 7) out = yg @ W_out   [1024,1024], dtype per flag
    gemm_k<2><<<dim3(16, 16), 256, 0, stream>>>(yg, W_out_b, d_out, 1024, 1024, 2048, flag);
}

// Round 4
// 308.485 us; speedup vs baseline: 3.4520x; 1.0963x over previous
//
#include <hip/hip_runtime.h>

typedef unsigned short u16;
typedef unsigned int u32;
typedef __attribute__((ext_vector_type(8))) short bf16x8;
typedef __attribute__((ext_vector_type(4))) float f32x4;

#define LSEQ 1024

__device__ __forceinline__ float b2f(u16 v) { return __uint_as_float(((u32)v) << 16); }
__device__ __forceinline__ u16 f2b(float f) {
    u32 x = __float_as_uint(f);
    return (u16)((x + 0x7fffu + ((x >> 16) & 1u)) >> 16);
}
__device__ __forceinline__ float rdf(const void* p, int i, int f) {
    return f ? b2f(((const u16*)p)[i]) : ((const float*)p)[i];
}
// fast sigmoid via v_exp + v_rcp
__device__ __forceinline__ float fsig(float x) {
    return __builtin_amdgcn_rcpf(1.f + __expf(-x));
}

// ---------------- dtype detection ----------------
__global__ void detect_k(const u16* __restrict__ x, int* __restrict__ flag) {
    __shared__ int cnt;
    if (threadIdx.x == 0) cnt = 0;
    __syncthreads();
    int c = 0;
#pragma unroll
    for (int j = 0; j < 8; ++j) {
        u16 u = x[threadIdx.x * 8 + j];
        int e = (u >> 7) & 0xFF;
        c += (e == 0 || (e >= 100 && e <= 140)) ? 1 : 0;
    }
    atomicAdd(&cnt, c);
    __syncthreads();
    if (threadIdx.x == 0) *flag = (cnt >= 1638) ? 1 : 0;
}

// ---------------- fused canonicalization of 5 tensors to bf16 ----------------
__global__ __launch_bounds__(256) void cvtall_k(const void* s0, const void* s1,
                                                const void* s2, const void* s3,
                                                const void* s4,
                                                u16* d0, u16* d1, u16* d2, u16* d3, u16* d4,
                                                const int* __restrict__ flag) {
    int f = *flag;
    int i = blockIdx.x * 256 + threadIdx.x;  // over 7667712
    const void* s; u16* d; int off;
    if (i < 1048576)      { s = s0; d = d0; off = i; }
    else if (i < 5242880) { s = s1; d = d1; off = i - 1048576; }
    else if (i < 5439488) { s = s2; d = d2; off = i - 5242880; }
    else if (i < 5570560) { s = s3; d = d3; off = i - 5439488; }
    else                  { s = s4; d = d4; off = i - 5570560; }
    d[off] = f ? ((const u16*)s)[off] : f2b(((const float*)s)[off]);
}

// ---------------- GEMM: C[M,N] = A[M,K]*B[K,N], bf16 in, fp32 acc ----------------
// OUT_MODE: 0=fp32, 1=bf16, 2=dual(flag), 3=fp32 + bf16 copy of cols<64 into aux,
//           4=softplus(v + bias[col]) fp32
template <int OUT_MODE>
__global__ __launch_bounds__(256) void gemm_k(const u16* __restrict__ A,
                                              const u16* __restrict__ B,
                                              void* __restrict__ C,
                                              int M, int N, int K,
                                              const int* __restrict__ flag,
                                              u16* __restrict__ aux,
                                              const void* __restrict__ bias) {
    __shared__ __align__(16) u16 As[64 * 56];
    __shared__ __align__(16) u16 Bs[64 * 56];
    const int tid = threadIdx.x;
    const int wid = tid >> 6, lane = tid & 63;
    const int wm = wid & 1, wn = wid >> 1;
    const int m_blk = blockIdx.x * 64, n_blk = blockIdx.y * 64;
    const int lm = lane & 15, lq = lane >> 4;
    const int ar = tid >> 2, ac = (tid & 3) << 3;
    const int bn = tid & 63, bk = (tid >> 6) << 3;
    const int gn = n_blk + bn;
    const int f = (OUT_MODE == 2 || OUT_MODE == 4) ? flag[0] : 0;

    f32x4 zero = {0.f, 0.f, 0.f, 0.f};
    f32x4 acc[2][2];
    acc[0][0] = zero; acc[0][1] = zero; acc[1][0] = zero; acc[1][1] = zero;

    for (int kb = 0; kb < K; kb += 32) {
        bf16x8 av = *(const bf16x8*)(A + (size_t)(m_blk + ar) * K + kb + ac);
        short bv[8];
        if (gn < N) {
#pragma unroll
            for (int j = 0; j < 8; ++j) bv[j] = (short)B[(size_t)(kb + bk + j) * N + gn];
        } else {
#pragma unroll
            for (int j = 0; j < 8; ++j) bv[j] = 0;
        }
        __syncthreads();
        *(bf16x8*)(As + ar * 56 + ac) = av;
        bf16x8 bvv;
#pragma unroll
        for (int j = 0; j < 8; ++j) bvv[j] = bv[j];
        *(bf16x8*)(Bs + bn * 56 + bk) = bvv;
        __syncthreads();

        bf16x8 af0 = *(const bf16x8*)(As + (wm * 32 + lm) * 56 + lq * 8);
        bf16x8 af1 = *(const bf16x8*)(As + (wm * 32 + 16 + lm) * 56 + lq * 8);
        bf16x8 bf0 = *(const bf16x8*)(Bs + (wn * 32 + lm) * 56 + lq * 8);
        bf16x8 bf1 = *(const bf16x8*)(Bs + (wn * 32 + 16 + lm) * 56 + lq * 8);
        acc[0][0] = __builtin_amdgcn_mfma_f32_16x16x32_bf16(af0, bf0, acc[0][0], 0, 0, 0);
        acc[0][1] = __builtin_amdgcn_mfma_f32_16x16x32_bf16(af0, bf1, acc[0][1], 0, 0, 0);
        acc[1][0] = __builtin_amdgcn_mfma_f32_16x16x32_bf16(af1, bf0, acc[1][0], 0, 0, 0);
        acc[1][1] = __builtin_amdgcn_mfma_f32_16x16x32_bf16(af1, bf1, acc[1][1], 0, 0, 0);
    }

#pragma unroll
    for (int tm = 0; tm < 2; ++tm)
#pragma unroll
        for (int tn = 0; tn < 2; ++tn)
#pragma unroll
            for (int r = 0; r < 4; ++r) {
                int row = m_blk + wm * 32 + tm * 16 + lq * 4 + r;
                int col = n_blk + wn * 32 + tn * 16 + lm;
                if (col < N) {
                    float v = acc[tm][tn][r];
                    if (OUT_MODE == 0) {
                        ((float*)C)[(size_t)row * N + col] = v;
                    } else if (OUT_MODE == 1) {
                        ((u16*)C)[(size_t)row * N + col] = f2b(v);
                    } else if (OUT_MODE == 2) {
                        if (f) ((u16*)C)[(size_t)row * N + col] = f2b(v);
                        else   ((float*)C)[(size_t)row * N + col] = v;
                    } else if (OUT_MODE == 3) {
                        ((float*)C)[(size_t)row * N + col] = v;
                        if (col < 64) aux[(size_t)row * 64 + col] = f2b(v);
                    } else {  // 4: softplus(v + bias[col])
                        float b = rdf(bias, col, f);
                        float t = v + b;
                        float sp = fmaxf(t, 0.f) + __logf(1.f + __expf(-fabsf(t)));
                        ((float*)C)[(size_t)row * N + col] = sp;
                    }
                }
            }
}

// ---------------- causal depthwise conv (K=4) + SiLU ----------------
__global__ __launch_bounds__(256) void conv_silu_k(const u16* __restrict__ xz,
                                                   const void* __restrict__ cw,
                                                   const void* __restrict__ cb,
                                                   u16* __restrict__ xc,
                                                   const int* __restrict__ flag) {
    int f = *flag;
    int idx = blockIdx.x * 256 + threadIdx.x;  // over 1024*2048
    int t = idx >> 11, d = idx & 2047;
    float acc = rdf(cb, d, f);
#pragma unroll
    for (int k = 0; k < 4; ++k) {
        int tt = t + k - 3;
        if (tt >= 0) acc += b2f(xz[(size_t)tt * 4096 + d]) * rdf(cw, d * 4 + k, f);
    }
    xc[idx] = f2b(acc * fsig(acc));
}

// ---------------- chunked selective scan ----------------
// pass 1: per (chunk,d,n) local scan from h=0; store decay product and local state
template <int T>
__global__ __launch_bounds__(256) void scan1_k(const float* __restrict__ delta,
                                               const u16* __restrict__ xc,
                                               const float* __restrict__ xdbl,
                                               const void* __restrict__ A_log,
                                               float* __restrict__ Acar,
                                               float* __restrict__ Bcar,
                                               const int* __restrict__ flag) {
    int f = *flag;
    int g = blockIdx.x * 256 + threadIdx.x;  // over C*32768
    int c = g >> 15, rem = g & 32767;
    int d = rem >> 4, n = rem & 15;
    float A = -__expf(rdf(A_log, d * 16 + n, f));
    float P = 1.f, hl = 0.f;
    int t0 = c * T;
#pragma unroll 4
    for (int i = 0; i < T; ++i) {
        int t = t0 + i;
        float de = delta[t * 2048 + d];
        float u = b2f(xc[t * 2048 + d]);
        float Bv = xdbl[t * 96 + 64 + n];
        float a = __expf(de * A);
        hl = a * hl + (de * Bv) * u;
        P *= a;
    }
    Acar[g] = P;
    Bcar[g] = hl;
}

// pass 2: sequential combine over chunks; Bcar[c] <- state entering chunk c (in place)
__global__ __launch_bounds__(256) void scan2_k(const float* __restrict__ Acar,
                                               float* __restrict__ Bcar, int C) {
    int idx = blockIdx.x * 256 + threadIdx.x;  // over 32768
    float H = 0.f;
    for (int c = 0; c < C; ++c) {
        float a = Acar[c * 32768 + idx];
        float b = Bcar[c * 32768 + idx];
        Bcar[c * 32768 + idx] = H;
        H = a * H + b;
    }
}

// pass 3: re-run recurrence seeded with carry, reduce over n, gate, write yg
template <int T>
__global__ __launch_bounds__(256) void scan3_k(const float* __restrict__ delta,
                                               const u16* __restrict__ xc,
                                               const float* __restrict__ xdbl,
                                               const u16* __restrict__ xz,
                                               const void* __restrict__ A_log,
                                               const void* __restrict__ Dvp,
                                               const float* __restrict__ Bcar,
                                               u16* __restrict__ yg,
                                               const int* __restrict__ flag) {
    int f = *flag;
    int g = blockIdx.x * 256 + threadIdx.x;  // over C*32768
    int c = g >> 15, rem = g & 32767;
    int d = rem >> 4, n = rem & 15;
    float A = -__expf(rdf(A_log, d * 16 + n, f));
    float Dd = rdf(Dvp, d, f);
    float h = Bcar[g];
    int t0 = c * T;
#pragma unroll 4
    for (int i = 0; i < T; ++i) {
        int t = t0 + i;
        float de = delta[t * 2048 + d];
        float u = b2f(xc[t * 2048 + d]);
        float Bv = xdbl[t * 96 + 64 + n];
        float Cv = xdbl[t * 96 + 80 + n];
        h = __expf(de * A) * h + (de * Bv) * u;
        float p = h * Cv;
        p += __shfl_xor(p, 1);
        p += __shfl_xor(p, 2);
        p += __shfl_xor(p, 4);
        p += __shfl_xor(p, 8);
        if (n == 0) {
            float r = b2f(xz[(size_t)t * 4096 + 2048 + d]);
            float yt = p + u * Dd;
            yg[t * 2048 + d] = f2b(yt * r * fsig(r));
        }
    }
}

// fallback monolithic scan (only if ws too small for carries)
__global__ __launch_bounds__(256) void scan_k(const float* __restrict__ delta,
                                              const u16* __restrict__ xc,
                                              const float* __restrict__ xdbl,
                                              const u16* __restrict__ xz,
                                              const void* __restrict__ A_log,
                                              const void* __restrict__ Dvp,
                                              u16* __restrict__ yg,
                                              const int* __restrict__ flag) {
    int f = *flag;
    int g = blockIdx.x * 256 + threadIdx.x;
    int d = g >> 4, n = g & 15;
    float A = -__expf(rdf(A_log, d * 16 + n, f));
    float Dd = rdf(Dvp, d, f);
    float h = 0.f;
    for (int t = 0; t < LSEQ; ++t) {
        float de = delta[t * 2048 + d];
        float u = b2f(xc[t * 2048 + d]);
        float Bv = xdbl[t * 96 + 64 + n];
        float Cv = xdbl[t * 96 + 80 + n];
        h = __expf(de * A) * h + (de * Bv) * u;
        float p = h * Cv;
        p += __shfl_xor(p, 1);
        p += __shfl_xor(p, 2);
        p += __shfl_xor(p, 4);
        p += __shfl_xor(p, 8);
        if (n == 0) {
            float r = b2f(xz[(size_t)t * 4096 + 2048 + d]);
            float yt = p + u * Dd;
            yg[t * 2048 + d] = f2b(yt * r * fsig(r));
        }
    }
}

extern "C" void kernel_launch(void* const* d_in, const int* in_sizes, int n_in,
                              void* d_out, int out_size, void* d_ws, size_t ws_size,
                              hipStream_t stream) {
    const void* x      = d_in[0];
    const void* W_in   = d_in[1];
    const void* conv_w = d_in[2];
    const void* conv_b = d_in[3];
    const void* W_x    = d_in[4];
    const void* W_dt   = d_in[5];
    const void* b_dt   = d_in[6];
    const void* A_log  = d_in[7];
    const void* Dv     = d_in[8];
    const void* W_out  = d_in[9];

    char* ws = (char*)d_ws;
    u16*   xz     = (u16*)(ws);               // 8388608 B
    u16*   xconv  = (u16*)(ws + 8388608);     // 4194304 B
    float* xdbl   = (float*)(ws + 12582912);  // 393216 B
    u16*   dtb    = (u16*)(ws + 12976128);    // 131072 B
    float* delta  = (float*)(ws + 13107200);  // 8388608 B
    u16*   W_in_b = (u16*)(ws + 13107200);    // alias: GEMM1 only (before delta written)
    u16*   yg     = (u16*)(ws + 21495808);    // 4194304 B
    u16*   xb     = (u16*)(ws + 21495808);    // alias: GEMM1 only (before yg written)
    u16*   W_x_b  = (u16*)(ws + 25690112);    // 393216 B
    u16*   W_dt_b = (u16*)(ws + 26083328);    // 262144 B
    u16*   W_out_b= (u16*)(ws + 26345472);    // 4194304 B
    int*   flag   = (int*)(ws + 30539776);    // 4 B
    float* Acar   = (float*)(ws + 30539904);  // C*131072 B (Bcar follows)

    int C = 0;
    const size_t carry_base = 30539904;
    if (carry_base + (size_t)2 * 32 * 131072 <= ws_size) C = 32;
    else if (carry_base + (size_t)2 * 16 * 131072 <= ws_size) C = 16;
    else if (carry_base + (size_t)2 * 8 * 131072 <= ws_size) C = 8;
    float* Bcar = (C > 0) ? (float*)(ws + carry_base + (size_t)C * 131072) : nullptr;

    // 0) dtype detect + fused canonicalization (x, W_in, W_x, W_dt, W_out)
    detect_k<<<1, 256, 0, stream>>>((const u16*)x, flag);
    cvtall_k<<<29952, 256, 0, stream>>>(x, W_in, W_x, W_dt, W_out,
                                        xb, W_in_b, W_x_b, W_dt_b, W_out_b, flag);

    // 1) xz = x @ W_in   [1024,4096] bf16
    gemm_k<1><<<dim3(16, 64), 256, 0, stream>>>(xb, W_in_b, (void*)xz, 1024, 4096, 1024,
                                                flag, nullptr, nullptr);
    // 2) x_conv = silu(causal_dw_conv(x_in))
    conv_silu_k<<<8192, 256, 0, stream>>>(xz, conv_w, conv_b, xconv, flag);
    // 3) x_dbl = x_conv @ W_x   [1024,96] fp32  (+ dt cols -> bf16 dtb)
    gemm_k<3><<<dim3(16, 2), 256, 0, stream>>>(xconv, W_x_b, (void*)xdbl, 1024, 96, 2048,
                                               flag, dtb, nullptr);
    // 4) delta = softplus(dt @ W_dt + b_dt)   [1024,2048] fp32 (fused epilogue)
    gemm_k<4><<<dim3(16, 32), 256, 0, stream>>>(dtb, W_dt_b, (void*)delta, 1024, 2048, 64,
                                                flag, nullptr, b_dt);

    // 5) selective scan + gating -> yg bf16
    if (C == 32) {
        scan1_k<32><<<32 * 128, 256, 0, stream>>>(delta, xconv, xdbl, A_log, Acar, Bcar, flag);
        scan2_k<<<128, 256, 0, stream>>>(Acar, Bcar, 32);
        scan3_k<32><<<32 * 128, 256, 0, stream>>>(delta, xconv, xdbl, xz, A_log, Dv, Bcar, yg, flag);
    } else if (C == 16) {
        scan1_k<64><<<16 * 128, 256, 0, stream>>>(delta, xconv, xdbl, A_log, Acar, Bcar, flag);
        scan2_k<<<128, 256, 0, stream>>>(Acar, Bcar, 16);
        scan3_k<64><<<16 * 128, 256, 0, stream>>>(delta, xconv, xdbl, xz, A_log, Dv, Bcar, yg, flag);
    } else if (C == 8) {
        scan1_k<128><<<8 * 128, 256, 0, stream>>>(delta, xconv, xdbl, A_log, Acar, Bcar, flag);
        scan2_k<<<128, 256, 0, stream>>>(Acar, Bcar, 8);
        scan3_k<128><<<8 * 128, 256, 0, stream>>>(delta, xconv, xdbl, xz, A_log, Dv, Bcar, yg, flag);
    } else {
        scan_k<<<128, 256, 0, stream>>>(delta, xconv, xdbl, xz, A_log, Dv, yg, flag);
    }

    // 6) out = yg @ W_out   [1024,1024], dtype per flag
    gemm_k<2><<<dim3(16, 16), 256, 0, stream>>>(yg, W_out_b, d_out, 1024, 1024, 2048,
                                                flag, nullptr, nullptr);
}

// Round 5
// 280.050 us; speedup vs baseline: 3.8024x; 1.1015x over previous
//
#include <hip/hip_runtime.h>

typedef unsigned short u16;
typedef unsigned int u32;
typedef __attribute__((ext_vector_type(8))) short bf16x8;
typedef __attribute__((ext_vector_type(4))) float f32x4;

#define LSEQ 1024

__device__ __forceinline__ float b2f(u16 v) { return __uint_as_float(((u32)v) << 16); }
__device__ __forceinline__ u16 f2b(float f) {
    u32 x = __float_as_uint(f);
    return (u16)((x + 0x7fffu + ((x >> 16) & 1u)) >> 16);
}
__device__ __forceinline__ float rdf(const void* p, int i, int f) {
    return f ? b2f(((const u16*)p)[i]) : ((const float*)p)[i];
}
__device__ __forceinline__ float fsig(float x) {
    return __builtin_amdgcn_rcpf(1.f + __expf(-x));
}

// ---------------- dtype detection ----------------
__global__ void detect_k(const u16* __restrict__ x, int* __restrict__ flag) {
    __shared__ int cnt;
    if (threadIdx.x == 0) cnt = 0;
    __syncthreads();
    int c = 0;
#pragma unroll
    for (int j = 0; j < 8; ++j) {
        u16 u = x[threadIdx.x * 8 + j];
        int e = (u >> 7) & 0xFF;
        c += (e == 0 || (e >= 100 && e <= 140)) ? 1 : 0;
    }
    atomicAdd(&cnt, c);
    __syncthreads();
    if (threadIdx.x == 0) *flag = (cnt >= 1638) ? 1 : 0;
}

// ---------------- fused canonicalization of 5 tensors to bf16 ----------------
__global__ __launch_bounds__(256) void cvtall_k(const void* s0, const void* s1,
                                                const void* s2, const void* s3,
                                                const void* s4,
                                                u16* d0, u16* d1, u16* d2, u16* d3, u16* d4,
                                                const int* __restrict__ flag) {
    int f = *flag;
    int i = blockIdx.x * 256 + threadIdx.x;  // over 7667712
    const void* s; u16* d; int off;
    if (i < 1048576)      { s = s0; d = d0; off = i; }
    else if (i < 5242880) { s = s1; d = d1; off = i - 1048576; }
    else if (i < 5439488) { s = s2; d = d2; off = i - 5242880; }
    else if (i < 5570560) { s = s3; d = d3; off = i - 5439488; }
    else                  { s = s4; d = d4; off = i - 5570560; }
    d[off] = f ? ((const u16*)s)[off] : f2b(((const float*)s)[off]);
}

// ---------------- GEMM: C[M,N] = A[M,K]*B[K,N], bf16 in, fp32 acc ----------------
// OUT_MODE: 0=fp32, 1=bf16, 2=dual(flag), 3=fp32 + bf16 copy of cols<64 into aux,
//           4=softplus(v + bias[col]) fp32
template <int OUT_MODE>
__global__ __launch_bounds__(256) void gemm_k(const u16* __restrict__ A,
                                              const u16* __restrict__ B,
                                              void* __restrict__ C,
                                              int M, int N, int K,
                                              const int* __restrict__ flag,
                                              u16* __restrict__ aux,
                                              const void* __restrict__ bias) {
    __shared__ __align__(16) u16 As[64 * 56];
    __shared__ __align__(16) u16 Bs[64 * 56];
    const int tid = threadIdx.x;
    const int wid = tid >> 6, lane = tid & 63;
    const int wm = wid & 1, wn = wid >> 1;
    const int m_blk = blockIdx.x * 64, n_blk = blockIdx.y * 64;
    const int lm = lane & 15, lq = lane >> 4;
    const int ar = tid >> 2, ac = (tid & 3) << 3;
    const int bn = tid & 63, bk = (tid >> 6) << 3;
    const int gn = n_blk + bn;
    const int f = (OUT_MODE == 2 || OUT_MODE == 4) ? flag[0] : 0;

    f32x4 zero = {0.f, 0.f, 0.f, 0.f};
    f32x4 acc[2][2];
    acc[0][0] = zero; acc[0][1] = zero; acc[1][0] = zero; acc[1][1] = zero;

    for (int kb = 0; kb < K; kb += 32) {
        bf16x8 av = *(const bf16x8*)(A + (size_t)(m_blk + ar) * K + kb + ac);
        short bv[8];
        if (gn < N) {
#pragma unroll
            for (int j = 0; j < 8; ++j) bv[j] = (short)B[(size_t)(kb + bk + j) * N + gn];
        } else {
#pragma unroll
            for (int j = 0; j < 8; ++j) bv[j] = 0;
        }
        __syncthreads();
        *(bf16x8*)(As + ar * 56 + ac) = av;
        bf16x8 bvv;
#pragma unroll
        for (int j = 0; j < 8; ++j) bvv[j] = bv[j];
        *(bf16x8*)(Bs + bn * 56 + bk) = bvv;
        __syncthreads();

        bf16x8 af0 = *(const bf16x8*)(As + (wm * 32 + lm) * 56 + lq * 8);
        bf16x8 af1 = *(const bf16x8*)(As + (wm * 32 + 16 + lm) * 56 + lq * 8);
        bf16x8 bf0 = *(const bf16x8*)(Bs + (wn * 32 + lm) * 56 + lq * 8);
        bf16x8 bf1 = *(const bf16x8*)(Bs + (wn * 32 + 16 + lm) * 56 + lq * 8);
        acc[0][0] = __builtin_amdgcn_mfma_f32_16x16x32_bf16(af0, bf0, acc[0][0], 0, 0, 0);
        acc[0][1] = __builtin_amdgcn_mfma_f32_16x16x32_bf16(af0, bf1, acc[0][1], 0, 0, 0);
        acc[1][0] = __builtin_amdgcn_mfma_f32_16x16x32_bf16(af1, bf0, acc[1][0], 0, 0, 0);
        acc[1][1] = __builtin_amdgcn_mfma_f32_16x16x32_bf16(af1, bf1, acc[1][1], 0, 0, 0);
    }

#pragma unroll
    for (int tm = 0; tm < 2; ++tm)
#pragma unroll
        for (int tn = 0; tn < 2; ++tn)
#pragma unroll
            for (int r = 0; r < 4; ++r) {
                int row = m_blk + wm * 32 + tm * 16 + lq * 4 + r;
                int col = n_blk + wn * 32 + tn * 16 + lm;
                if (col < N) {
                    float v = acc[tm][tn][r];
                    if (OUT_MODE == 0) {
                        ((float*)C)[(size_t)row * N + col] = v;
                    } else if (OUT_MODE == 1) {
                        ((u16*)C)[(size_t)row * N + col] = f2b(v);
                    } else if (OUT_MODE == 2) {
                        if (f) ((u16*)C)[(size_t)row * N + col] = f2b(v);
                        else   ((float*)C)[(size_t)row * N + col] = v;
                    } else if (OUT_MODE == 3) {
                        ((float*)C)[(size_t)row * N + col] = v;
                        if (col < 64) aux[(size_t)row * 64 + col] = f2b(v);
                    } else {  // 4: softplus(v + bias[col])
                        float b = rdf(bias, col, f);
                        float t = v + b;
                        float sp = fmaxf(t, 0.f) + __logf(1.f + __expf(-fabsf(t)));
                        ((float*)C)[(size_t)row * N + col] = sp;
                    }
                }
            }
}

// ---------------- causal depthwise conv (K=4) + SiLU ----------------
__global__ __launch_bounds__(256) void conv_silu_k(const u16* __restrict__ xz,
                                                   const void* __restrict__ cw,
                                                   const void* __restrict__ cb,
                                                   u16* __restrict__ xc,
                                                   const int* __restrict__ flag) {
    int f = *flag;
    int idx = blockIdx.x * 256 + threadIdx.x;  // over 1024*2048
    int t = idx >> 11, d = idx & 2047;
    float acc = rdf(cb, d, f);
#pragma unroll
    for (int k = 0; k < 4; ++k) {
        int tt = t + k - 3;
        if (tt >= 0) acc += b2f(xz[(size_t)tt * 4096 + d]) * rdf(cw, d * 4 + k, f);
    }
    xc[idx] = f2b(acc * fsig(acc));
}

// ---------------- chunked selective scan, (d, n-half) per lane ----------------
// lane owns 8 n-states; lanes 2k/2k+1 share d (nh = bit0). Carries at [c][d][n].
// pass 1: local scan from h=0; store decay products P[8] and local states h[8]
template <int T>
__global__ __launch_bounds__(256) void scan1_k(const float* __restrict__ delta,
                                               const u16* __restrict__ xc,
                                               const float* __restrict__ xdbl,
                                               const void* __restrict__ A_log,
                                               float* __restrict__ Acar,
                                               float* __restrict__ Bcar,
                                               const int* __restrict__ flag) {
    int f = *flag;
    int g = blockIdx.x * 256 + threadIdx.x;  // over C*4096
    int c = g >> 12, rem = g & 4095;
    int d = rem >> 1, nh = rem & 1;
    int n0 = nh << 3;
    float A[8], P[8], h[8];
#pragma unroll
    for (int j = 0; j < 8; ++j) {
        A[j] = -__expf(rdf(A_log, d * 16 + n0 + j, f));
        P[j] = 1.f;
        h[j] = 0.f;
    }
    int t0 = c * T;
#pragma unroll 4
    for (int i = 0; i < T; ++i) {
        int t = t0 + i;
        float de = delta[t * 2048 + d];
        float dBu = de * b2f(xc[t * 2048 + d]);
        f32x4 Bv0 = *(const f32x4*)(xdbl + t * 96 + 64 + n0);
        f32x4 Bv1 = *(const f32x4*)(xdbl + t * 96 + 68 + n0);
#pragma unroll
        for (int j = 0; j < 8; ++j) {
            float Bv = (j < 4) ? Bv0[j & 3] : Bv1[j & 3];
            float a = __expf(de * A[j]);
            h[j] = a * h[j] + Bv * dBu;
            P[j] *= a;
        }
    }
    f32x4 pa0 = {P[0], P[1], P[2], P[3]}, pa1 = {P[4], P[5], P[6], P[7]};
    f32x4 hb0 = {h[0], h[1], h[2], h[3]}, hb1 = {h[4], h[5], h[6], h[7]};
    size_t base = (size_t)c * 32768 + d * 16 + n0;
    *(f32x4*)(Acar + base) = pa0;
    *(f32x4*)(Acar + base + 4) = pa1;
    *(f32x4*)(Bcar + base) = hb0;
    *(f32x4*)(Bcar + base + 4) = hb1;
}

// pass 2: sequential combine over chunks; Bcar[c] <- state entering chunk c (in place)
__global__ __launch_bounds__(256) void scan2_k(const float* __restrict__ Acar,
                                               float* __restrict__ Bcar, int C) {
    int idx = blockIdx.x * 256 + threadIdx.x;  // over 32768
    float H = 0.f;
    for (int c = 0; c < C; ++c) {
        float a = Acar[c * 32768 + idx];
        float b = Bcar[c * 32768 + idx];
        Bcar[c * 32768 + idx] = H;
        H = a * H + b;
    }
}

// pass 3: re-run recurrence seeded with carry; dot over 16 n (8 in-reg + 1 shuffle), gate
template <int T>
__global__ __launch_bounds__(256) void scan3_k(const float* __restrict__ delta,
                                               const u16* __restrict__ xc,
                                               const float* __restrict__ xdbl,
                                               const u16* __restrict__ xz,
                                               const void* __restrict__ A_log,
                                               const void* __restrict__ Dvp,
                                               const float* __restrict__ Bcar,
                                               u16* __restrict__ yg,
                                               const int* __restrict__ flag) {
    int f = *flag;
    int g = blockIdx.x * 256 + threadIdx.x;  // over C*4096
    int c = g >> 12, rem = g & 4095;
    int d = rem >> 1, nh = rem & 1;
    int n0 = nh << 3;
    float A[8], h[8];
    size_t base = (size_t)c * 32768 + d * 16 + n0;
    f32x4 h0 = *(const f32x4*)(Bcar + base);
    f32x4 h1 = *(const f32x4*)(Bcar + base + 4);
#pragma unroll
    for (int j = 0; j < 8; ++j) {
        A[j] = -__expf(rdf(A_log, d * 16 + n0 + j, f));
        h[j] = (j < 4) ? h0[j & 3] : h1[j & 3];
    }
    float Dd = rdf(Dvp, d, f);
    int t0 = c * T;
#pragma unroll 4
    for (int i = 0; i < T; ++i) {
        int t = t0 + i;
        float de = delta[t * 2048 + d];
        float u = b2f(xc[t * 2048 + d]);
        float dBu = de * u;
        f32x4 Bv0 = *(const f32x4*)(xdbl + t * 96 + 64 + n0);
        f32x4 Bv1 = *(const f32x4*)(xdbl + t * 96 + 68 + n0);
        f32x4 Cv0 = *(const f32x4*)(xdbl + t * 96 + 80 + n0);
        f32x4 Cv1 = *(const f32x4*)(xdbl + t * 96 + 84 + n0);
        float p = 0.f;
#pragma unroll
        for (int j = 0; j < 8; ++j) {
            float Bv = (j < 4) ? Bv0[j & 3] : Bv1[j & 3];
            float Cv = (j < 4) ? Cv0[j & 3] : Cv1[j & 3];
            float a = __expf(de * A[j]);
            h[j] = a * h[j] + Bv * dBu;
            p += h[j] * Cv;
        }
        p += __shfl_xor(p, 1);  // combine the two n-halves (lanes 2k,2k+1 share d)
        if (nh == 0) {
            float r = b2f(xz[(size_t)t * 4096 + 2048 + d]);
            float yt = p + u * Dd;
            yg[t * 2048 + d] = f2b(yt * r * fsig(r));
        }
    }
}

// fallback monolithic scan (only if ws too small for carries)
__global__ __launch_bounds__(256) void scan_k(const float* __restrict__ delta,
                                              const u16* __restrict__ xc,
                                              const float* __restrict__ xdbl,
                                              const u16* __restrict__ xz,
                                              const void* __restrict__ A_log,
                                              const void* __restrict__ Dvp,
                                              u16* __restrict__ yg,
                                              const int* __restrict__ flag) {
    int f = *flag;
    int g = blockIdx.x * 256 + threadIdx.x;
    int d = g >> 4, n = g & 15;
    float A = -__expf(rdf(A_log, d * 16 + n, f));
    float Dd = rdf(Dvp, d, f);
    float h = 0.f;
    for (int t = 0; t < LSEQ; ++t) {
        float de = delta[t * 2048 + d];
        float u = b2f(xc[t * 2048 + d]);
        float Bv = xdbl[t * 96 + 64 + n];
        float Cv = xdbl[t * 96 + 80 + n];
        h = __expf(de * A) * h + (de * Bv) * u;
        float p = h * Cv;
        p += __shfl_xor(p, 1);
        p += __shfl_xor(p, 2);
        p += __shfl_xor(p, 4);
        p += __shfl_xor(p, 8);
        if (n == 0) {
            float r = b2f(xz[(size_t)t * 4096 + 2048 + d]);
            float yt = p + u * Dd;
            yg[t * 2048 + d] = f2b(yt * r * fsig(r));
        }
    }
}

extern "C" void kernel_launch(void* const* d_in, const int* in_sizes, int n_in,
                              void* d_out, int out_size, void* d_ws, size_t ws_size,
                              hipStream_t stream) {
    const void* x      = d_in[0];
    const void* W_in   = d_in[1];
    const void* conv_w = d_in[2];
    const void* conv_b = d_in[3];
    const void* W_x    = d_in[4];
    const void* W_dt   = d_in[5];
    const void* b_dt   = d_in[6];
    const void* A_log  = d_in[7];
    const void* Dv     = d_in[8];
    const void* W_out  = d_in[9];

    char* ws = (char*)d_ws;
    u16*   xz     = (u16*)(ws);               // 8388608 B
    u16*   xconv  = (u16*)(ws + 8388608);     // 4194304 B
    float* xdbl   = (float*)(ws + 12582912);  // 393216 B
    u16*   dtb    = (u16*)(ws + 12976128);    // 131072 B
    float* delta  = (float*)(ws + 13107200);  // 8388608 B
    u16*   W_in_b = (u16*)(ws + 13107200);    // alias: GEMM1 only (before delta written)
    u16*   yg     = (u16*)(ws + 21495808);    // 4194304 B
    u16*   xb     = (u16*)(ws + 21495808);    // alias: GEMM1 only (before yg written)
    u16*   W_x_b  = (u16*)(ws + 25690112);    // 393216 B
    u16*   W_dt_b = (u16*)(ws + 26083328);    // 262144 B
    u16*   W_out_b= (u16*)(ws + 26345472);    // 4194304 B
    int*   flag   = (int*)(ws + 30539776);    // 4 B
    float* Acar   = (float*)(ws + 30539904);  // C*131072 B (Bcar follows)

    int C = 0;
    const size_t carry_base = 30539904;
    if (carry_base + (size_t)2 * 32 * 131072 <= ws_size) C = 32;
    else if (carry_base + (size_t)2 * 16 * 131072 <= ws_size) C = 16;
    else if (carry_base + (size_t)2 * 8 * 131072 <= ws_size) C = 8;
    float* Bcar = (C > 0) ? (float*)(ws + carry_base + (size_t)C * 131072) : nullptr;

    // 0) dtype detect + fused canonicalization (x, W_in, W_x, W_dt, W_out)
    detect_k<<<1, 256, 0, stream>>>((const u16*)x, flag);
    cvtall_k<<<29952, 256, 0, stream>>>(x, W_in, W_x, W_dt, W_out,
                                        xb, W_in_b, W_x_b, W_dt_b, W_out_b, flag);

    // 1) xz = x @ W_in   [1024,4096] bf16
    gemm_k<1><<<dim3(16, 64), 256, 0, stream>>>(xb, W_in_b, (void*)xz, 1024, 4096, 1024,
                                                flag, nullptr, nullptr);
    // 2) x_conv = silu(causal_dw_conv(x_in))
    conv_silu_k<<<8192, 256, 0, stream>>>(xz, conv_w, conv_b, xconv, flag);
    // 3) x_dbl = x_conv @ W_x   [1024,96] fp32  (+ dt cols -> bf16 dtb)
    gemm_k<3><<<dim3(16, 2), 256, 0, stream>>>(xconv, W_x_b, (void*)xdbl, 1024, 96, 2048,
                                               flag, dtb, nullptr);
    // 4) delta = softplus(dt @ W_dt + b_dt)   [1024,2048] fp32 (fused epilogue)
    gemm_k<4><<<dim3(16, 32), 256, 0, stream>>>(dtb, W_dt_b, (void*)delta, 1024, 2048, 64,
                                                flag, nullptr, b_dt);

    // 5) selective scan + gating -> yg bf16
    if (C == 32) {
        scan1_k<32><<<512, 256, 0, stream>>>(delta, xconv, xdbl, A_log, Acar, Bcar, flag);
        scan2_k<<<128, 256, 0, stream>>>(Acar, Bcar, 32);
        scan3_k<32><<<512, 256, 0, stream>>>(delta, xconv, xdbl, xz, A_log, Dv, Bcar, yg, flag);
    } else if (C == 16) {
        scan1_k<64><<<256, 256, 0, stream>>>(delta, xconv, xdbl, A_log, Acar, Bcar, flag);
        scan2_k<<<128, 256, 0, stream>>>(Acar, Bcar, 16);
        scan3_k<64><<<256, 256, 0, stream>>>(delta, xconv, xdbl, xz, A_log, Dv, Bcar, yg, flag);
    } else if (C == 8) {
        scan1_k<128><<<128, 256, 0, stream>>>(delta, xconv, xdbl, A_log, Acar, Bcar, flag);
        scan2_k<<<128, 256, 0, stream>>>(Acar, Bcar, 8);
        scan3_k<128><<<128, 256, 0, stream>>>(delta, xconv, xdbl, xz, A_log, Dv, Bcar, yg, flag);
    } else {
        scan_k<<<128, 256, 0, stream>>>(delta, xconv, xdbl, xz, A_log, Dv, yg, flag);
    }

    // 6) out = yg @ W_out   [1024,1024], dtype per flag
    gemm_k<2><<<dim3(16, 16), 256, 0, stream>>>(yg, W_out_b, d_out, 1024, 1024, 2048,
                                                flag, nullptr, nullptr);
}

// Round 6
// 273.531 us; speedup vs baseline: 3.8931x; 1.0238x over previous
//
#include <hip/hip_runtime.h>

typedef unsigned short u16;
typedef unsigned int u32;
typedef __attribute__((ext_vector_type(8))) short bf16x8;
typedef __attribute__((ext_vector_type(4))) float f32x4;

#define LSEQ 1024

__device__ __forceinline__ float b2f(u16 v) { return __uint_as_float(((u32)v) << 16); }
__device__ __forceinline__ u16 f2b(float f) {
    u32 x = __float_as_uint(f);
    return (u16)((x + 0x7fffu + ((x >> 16) & 1u)) >> 16);
}
__device__ __forceinline__ float rdf(const void* p, int i, int f) {
    return f ? b2f(((const u16*)p)[i]) : ((const float*)p)[i];
}
__device__ __forceinline__ float fsig(float x) {
    return __builtin_amdgcn_rcpf(1.f + __expf(-x));
}

typedef const __attribute__((address_space(1))) u32* gp_t;
typedef __attribute__((address_space(3))) u32* lp_t;
// async global->LDS, 16B per lane; LDS dest = wave-uniform base + lane*16
__device__ __forceinline__ void gload16(const u16* g, u16* lds_wave_base) {
    __builtin_amdgcn_global_load_lds((gp_t)g, (lp_t)lds_wave_base, 16, 0, 0);
}

// ---------------- dtype detection ----------------
__global__ void detect_k(const u16* __restrict__ x, int* __restrict__ flag) {
    __shared__ int cnt;
    if (threadIdx.x == 0) cnt = 0;
    __syncthreads();
    int c = 0;
#pragma unroll
    for (int j = 0; j < 8; ++j) {
        u16 u = x[threadIdx.x * 8 + j];
        int e = (u >> 7) & 0xFF;
        c += (e == 0 || (e >= 100 && e <= 140)) ? 1 : 0;
    }
    atomicAdd(&cnt, c);
    __syncthreads();
    if (threadIdx.x == 0) *flag = (cnt >= 1638) ? 1 : 0;
}

// ---------------- fused canonicalization (x, W_x, W_dt) to bf16 ----------------
__global__ __launch_bounds__(256) void cvtall_k(const void* s0, const void* s1,
                                                const void* s2,
                                                u16* d0, u16* d1, u16* d2,
                                                const int* __restrict__ flag) {
    int f = *flag;
    int i = blockIdx.x * 256 + threadIdx.x;  // over 1376256
    const void* s; u16* d; int off;
    if (i < 1048576)      { s = s0; d = d0; off = i; }
    else if (i < 1245184) { s = s1; d = d1; off = i - 1048576; }
    else                  { s = s2; d = d2; off = i - 1245184; }
    d[off] = f ? ((const u16*)s)[off] : f2b(((const float*)s)[off]);
}

// ---------------- transpose + convert: src [R,Cn] -> dst [Cn,R] bf16 ----------------
__global__ __launch_bounds__(256) void tcvt_k(const void* __restrict__ src,
                                              u16* __restrict__ dst,
                                              int R, int Cn,
                                              const int* __restrict__ flag) {
    int f = *flag;
    __shared__ u16 tile[32][33];
    int r0 = blockIdx.x * 32, c0 = blockIdx.y * 32;
    int tx = threadIdx.x & 31, ty0 = threadIdx.x >> 5;  // 8 rows per pass
#pragma unroll
    for (int p = 0; p < 4; ++p) {
        int ty = ty0 + p * 8;
        tile[ty][tx] = f2b(rdf(src, (size_t)(r0 + ty) * Cn + c0 + tx, f));
    }
    __syncthreads();
#pragma unroll
    for (int p = 0; p < 4; ++p) {
        int ty = ty0 + p * 8;
        dst[(size_t)(c0 + ty) * R + r0 + tx] = tile[tx][ty];
    }
}

// ---------------- big GEMM, B transposed: C[M,N] = A[M,K] * Bt[N,K]^T ----------------
// 256 threads = 4 waves in 2x2. Wave-tile 16*MT x 16*NT, block tile 32*MT x 32*NT.
// global_load_lds width-16 staging into stride-32 (unpadded) LDS; ds_read_b128 frags.
// M % (32*MT) == 0, N % (32*NT) == 0, K % 32 == 0. OUT_MODE: 1=bf16, 2=dual(flag)
template <int MT, int NT, int OUT_MODE>
__global__ __launch_bounds__(256) void gemm_bt(const u16* __restrict__ A,
                                               const u16* __restrict__ Bt,
                                               void* __restrict__ C,
                                               int M, int N, int K,
                                               const int* __restrict__ flag) {
    constexpr int BM = 32 * MT, BN = 32 * NT;
    __shared__ __align__(16) u16 As[BM * 32];
    __shared__ __align__(16) u16 Bs[BN * 32];
    const int tid = threadIdx.x;
    const int w = tid >> 6, lane = tid & 63;
    const int wm = w & 1, wn = w >> 1;
    const int m_blk = blockIdx.x * BM, n_blk = blockIdx.y * BN;
    const int lm = lane & 15, lq = lane >> 4;
    const int sr = lane >> 2, sc = (lane & 3) << 3;  // staging: 16 rows x 32 cols per wave
    const int f = (OUT_MODE == 2) ? flag[0] : 0;

    f32x4 acc[MT][NT];
#pragma unroll
    for (int i = 0; i < MT; ++i)
#pragma unroll
        for (int j = 0; j < NT; ++j) acc[i][j] = (f32x4){0.f, 0.f, 0.f, 0.f};

    for (int kb = 0; kb < K; kb += 32) {
        __syncthreads();  // previous iter's LDS reads done before overwrite
#pragma unroll
        for (int i = 0; i < BM / 64; ++i) {
            int row = i * 64 + w * 16;
            gload16(A + (size_t)(m_blk + row + sr) * K + kb + sc, As + row * 32);
        }
#pragma unroll
        for (int i = 0; i < BN / 64; ++i) {
            int row = i * 64 + w * 16;
            gload16(Bt + (size_t)(n_blk + row + sr) * K + kb + sc, Bs + row * 32);
        }
        __syncthreads();  // drains vmcnt -> staged data visible

        bf16x8 af[MT], bf[NT];
#pragma unroll
        for (int tm = 0; tm < MT; ++tm)
            af[tm] = *(const bf16x8*)(As + (wm * 16 * MT + tm * 16 + lm) * 32 + lq * 8);
#pragma unroll
        for (int tn = 0; tn < NT; ++tn)
            bf[tn] = *(const bf16x8*)(Bs + (wn * 16 * NT + tn * 16 + lm) * 32 + lq * 8);
#pragma unroll
        for (int tm = 0; tm < MT; ++tm)
#pragma unroll
            for (int tn = 0; tn < NT; ++tn)
                acc[tm][tn] = __builtin_amdgcn_mfma_f32_16x16x32_bf16(af[tm], bf[tn],
                                                                      acc[tm][tn], 0, 0, 0);
    }

#pragma unroll
    for (int tm = 0; tm < MT; ++tm)
#pragma unroll
        for (int tn = 0; tn < NT; ++tn)
#pragma unroll
            for (int r = 0; r < 4; ++r) {
                int row = m_blk + wm * 16 * MT + tm * 16 + lq * 4 + r;
                int col = n_blk + wn * 16 * NT + tn * 16 + lm;
                float v = acc[tm][tn][r];
                if (OUT_MODE == 1) {
                    ((u16*)C)[(size_t)row * N + col] = f2b(v);
                } else {
                    if (f) ((u16*)C)[(size_t)row * N + col] = f2b(v);
                    else   ((float*)C)[(size_t)row * N + col] = v;
                }
            }
}

// ---------------- small GEMM (old structure): C[M,N] = A[M,K]*B[K,N] ----------------
// OUT_MODE: 3=fp32 + bf16 copy of cols<64 into aux, 4=softplus(v + bias[col]) fp32
template <int OUT_MODE>
__global__ __launch_bounds__(256) void gemm_k(const u16* __restrict__ A,
                                              const u16* __restrict__ B,
                                              void* __restrict__ C,
                                              int M, int N, int K,
                                              const int* __restrict__ flag,
                                              u16* __restrict__ aux,
                                              const void* __restrict__ bias) {
    __shared__ __align__(16) u16 As[64 * 56];
    __shared__ __align__(16) u16 Bs[64 * 56];
    const int tid = threadIdx.x;
    const int wid = tid >> 6, lane = tid & 63;
    const int wm = wid & 1, wn = wid >> 1;
    const int m_blk = blockIdx.x * 64, n_blk = blockIdx.y * 64;
    const int lm = lane & 15, lq = lane >> 4;
    const int ar = tid >> 2, ac = (tid & 3) << 3;
    const int bn = tid & 63, bk = (tid >> 6) << 3;
    const int gn = n_blk + bn;
    const int f = (OUT_MODE == 4) ? flag[0] : 0;

    f32x4 zero = {0.f, 0.f, 0.f, 0.f};
    f32x4 acc[2][2];
    acc[0][0] = zero; acc[0][1] = zero; acc[1][0] = zero; acc[1][1] = zero;

    for (int kb = 0; kb < K; kb += 32) {
        bf16x8 av = *(const bf16x8*)(A + (size_t)(m_blk + ar) * K + kb + ac);
        short bv[8];
        if (gn < N) {
#pragma unroll
            for (int j = 0; j < 8; ++j) bv[j] = (short)B[(size_t)(kb + bk + j) * N + gn];
        } else {
#pragma unroll
            for (int j = 0; j < 8; ++j) bv[j] = 0;
        }
        __syncthreads();
        *(bf16x8*)(As + ar * 56 + ac) = av;
        bf16x8 bvv;
#pragma unroll
        for (int j = 0; j < 8; ++j) bvv[j] = bv[j];
        *(bf16x8*)(Bs + bn * 56 + bk) = bvv;
        __syncthreads();

        bf16x8 af0 = *(const bf16x8*)(As + (wm * 32 + lm) * 56 + lq * 8);
        bf16x8 af1 = *(const bf16x8*)(As + (wm * 32 + 16 + lm) * 56 + lq * 8);
        bf16x8 bf0 = *(const bf16x8*)(Bs + (wn * 32 + lm) * 56 + lq * 8);
        bf16x8 bf1 = *(const bf16x8*)(Bs + (wn * 32 + 16 + lm) * 56 + lq * 8);
        acc[0][0] = __builtin_amdgcn_mfma_f32_16x16x32_bf16(af0, bf0, acc[0][0], 0, 0, 0);
        acc[0][1] = __builtin_amdgcn_mfma_f32_16x16x32_bf16(af0, bf1, acc[0][1], 0, 0, 0);
        acc[1][0] = __builtin_amdgcn_mfma_f32_16x16x32_bf16(af1, bf0, acc[1][0], 0, 0, 0);
        acc[1][1] = __builtin_amdgcn_mfma_f32_16x16x32_bf16(af1, bf1, acc[1][1], 0, 0, 0);
    }

#pragma unroll
    for (int tm = 0; tm < 2; ++tm)
#pragma unroll
        for (int tn = 0; tn < 2; ++tn)
#pragma unroll
            for (int r = 0; r < 4; ++r) {
                int row = m_blk + wm * 32 + tm * 16 + lq * 4 + r;
                int col = n_blk + wn * 32 + tn * 16 + lm;
                if (col < N) {
                    float v = acc[tm][tn][r];
                    if (OUT_MODE == 3) {
                        ((float*)C)[(size_t)row * N + col] = v;
                        if (col < 64) aux[(size_t)row * 64 + col] = f2b(v);
                    } else {  // 4: softplus(v + bias[col])
                        float b = rdf(bias, col, f);
                        float t = v + b;
                        float sp = fmaxf(t, 0.f) + __logf(1.f + __expf(-fabsf(t)));
                        ((float*)C)[(size_t)row * N + col] = sp;
                    }
                }
            }
}

// ---------------- causal depthwise conv (K=4) + SiLU ----------------
__global__ __launch_bounds__(256) void conv_silu_k(const u16* __restrict__ xz,
                                                   const void* __restrict__ cw,
                                                   const void* __restrict__ cb,
                                                   u16* __restrict__ xc,
                                                   const int* __restrict__ flag) {
    int f = *flag;
    int idx = blockIdx.x * 256 + threadIdx.x;  // over 1024*2048
    int t = idx >> 11, d = idx & 2047;
    float acc = rdf(cb, d, f);
#pragma unroll
    for (int k = 0; k < 4; ++k) {
        int tt = t + k - 3;
        if (tt >= 0) acc += b2f(xz[(size_t)tt * 4096 + d]) * rdf(cw, d * 4 + k, f);
    }
    xc[idx] = f2b(acc * fsig(acc));
}

// ---------------- chunked selective scan, (d, n-half) per lane ----------------
template <int T>
__global__ __launch_bounds__(256) void scan1_k(const float* __restrict__ delta,
                                               const u16* __restrict__ xc,
                                               const float* __restrict__ xdbl,
                                               const void* __restrict__ A_log,
                                               float* __restrict__ Acar,
                                               float* __restrict__ Bcar,
                                               const int* __restrict__ flag) {
    int f = *flag;
    int g = blockIdx.x * 256 + threadIdx.x;  // over C*4096
    int c = g >> 12, rem = g & 4095;
    int d = rem >> 1, nh = rem & 1;
    int n0 = nh << 3;
    float A[8], P[8], h[8];
#pragma unroll
    for (int j = 0; j < 8; ++j) {
        A[j] = -__expf(rdf(A_log, d * 16 + n0 + j, f));
        P[j] = 1.f;
        h[j] = 0.f;
    }
    int t0 = c * T;
#pragma unroll 4
    for (int i = 0; i < T; ++i) {
        int t = t0 + i;
        float de = delta[t * 2048 + d];
        float dBu = de * b2f(xc[t * 2048 + d]);
        f32x4 Bv0 = *(const f32x4*)(xdbl + t * 96 + 64 + n0);
        f32x4 Bv1 = *(const f32x4*)(xdbl + t * 96 + 68 + n0);
#pragma unroll
        for (int j = 0; j < 8; ++j) {
            float Bv = (j < 4) ? Bv0[j & 3] : Bv1[j & 3];
            float a = __expf(de * A[j]);
            h[j] = a * h[j] + Bv * dBu;
            P[j] *= a;
        }
    }
    f32x4 pa0 = {P[0], P[1], P[2], P[3]}, pa1 = {P[4], P[5], P[6], P[7]};
    f32x4 hb0 = {h[0], h[1], h[2], h[3]}, hb1 = {h[4], h[5], h[6], h[7]};
    size_t base = (size_t)c * 32768 + d * 16 + n0;
    *(f32x4*)(Acar + base) = pa0;
    *(f32x4*)(Acar + base + 4) = pa1;
    *(f32x4*)(Bcar + base) = hb0;
    *(f32x4*)(Bcar + base + 4) = hb1;
}

__global__ __launch_bounds__(256) void scan2_k(const float* __restrict__ Acar,
                                               float* __restrict__ Bcar, int C) {
    int idx = blockIdx.x * 256 + threadIdx.x;  // over 32768
    float H = 0.f;
    for (int c = 0; c < C; ++c) {
        float a = Acar[c * 32768 + idx];
        float b = Bcar[c * 32768 + idx];
        Bcar[c * 32768 + idx] = H;
        H = a * H + b;
    }
}

template <int T>
__global__ __launch_bounds__(256) void scan3_k(const float* __restrict__ delta,
                                               const u16* __restrict__ xc,
                                               const float* __restrict__ xdbl,
                                               const u16* __restrict__ xz,
                                               const void* __restrict__ A_log,
                                               const void* __restrict__ Dvp,
                                               const float* __restrict__ Bcar,
                                               u16* __restrict__ yg,
                                               const int* __restrict__ flag) {
    int f = *flag;
    int g = blockIdx.x * 256 + threadIdx.x;  // over C*4096
    int c = g >> 12, rem = g & 4095;
    int d = rem >> 1, nh = rem & 1;
    int n0 = nh << 3;
    float A[8], h[8];
    size_t base = (size_t)c * 32768 + d * 16 + n0;
    f32x4 h0 = *(const f32x4*)(Bcar + base);
    f32x4 h1 = *(const f32x4*)(Bcar + base + 4);
#pragma unroll
    for (int j = 0; j < 8; ++j) {
        A[j] = -__expf(rdf(A_log, d * 16 + n0 + j, f));
        h[j] = (j < 4) ? h0[j & 3] : h1[j & 3];
    }
    float Dd = rdf(Dvp, d, f);
    int t0 = c * T;
#pragma unroll 4
    for (int i = 0; i < T; ++i) {
        int t = t0 + i;
        float de = delta[t * 2048 + d];
        float u = b2f(xc[t * 2048 + d]);
        float dBu = de * u;
        f32x4 Bv0 = *(const f32x4*)(xdbl + t * 96 + 64 + n0);
        f32x4 Bv1 = *(const f32x4*)(xdbl + t * 96 + 68 + n0);
        f32x4 Cv0 = *(const f32x4*)(xdbl + t * 96 + 80 + n0);
        f32x4 Cv1 = *(const f32x4*)(xdbl + t * 96 + 84 + n0);
        float p = 0.f;
#pragma unroll
        for (int j = 0; j < 8; ++j) {
            float Bv = (j < 4) ? Bv0[j & 3] : Bv1[j & 3];
            float Cv = (j < 4) ? Cv0[j & 3] : Cv1[j & 3];
            float a = __expf(de * A[j]);
            h[j] = a * h[j] + Bv * dBu;
            p += h[j] * Cv;
        }
        p += __shfl_xor(p, 1);  // combine the two n-halves (lanes 2k,2k+1 share d)
        if (nh == 0) {
            float r = b2f(xz[(size_t)t * 4096 + 2048 + d]);
            float yt = p + u * Dd;
            yg[t * 2048 + d] = f2b(yt * r * fsig(r));
        }
    }
}

// fallback monolithic scan (only if ws too small for carries)
__global__ __launch_bounds__(256) void scan_k(const float* __restrict__ delta,
                                              const u16* __restrict__ xc,
                                              const float* __restrict__ xdbl,
                                              const u16* __restrict__ xz,
                                              const void* __restrict__ A_log,
                                              const void* __restrict__ Dvp,
                                              u16* __restrict__ yg,
                                              const int* __restrict__ flag) {
    int f = *flag;
    int g = blockIdx.x * 256 + threadIdx.x;
    int d = g >> 4, n = g & 15;
    float A = -__expf(rdf(A_log, d * 16 + n, f));
    float Dd = rdf(Dvp, d, f);
    float h = 0.f;
    for (int t = 0; t < LSEQ; ++t) {
        float de = delta[t * 2048 + d];
        float u = b2f(xc[t * 2048 + d]);
        float Bv = xdbl[t * 96 + 64 + n];
        float Cv = xdbl[t * 96 + 80 + n];
        h = __expf(de * A) * h + (de * Bv) * u;
        float p = h * Cv;
        p += __shfl_xor(p, 1);
        p += __shfl_xor(p, 2);
        p += __shfl_xor(p, 4);
        p += __shfl_xor(p, 8);
        if (n == 0) {
            float r = b2f(xz[(size_t)t * 4096 + 2048 + d]);
            float yt = p + u * Dd;
            yg[t * 2048 + d] = f2b(yt * r * fsig(r));
        }
    }
}

extern "C" void kernel_launch(void* const* d_in, const int* in_sizes, int n_in,
                              void* d_out, int out_size, void* d_ws, size_t ws_size,
                              hipStream_t stream) {
    const void* x      = d_in[0];
    const void* W_in   = d_in[1];
    const void* conv_w = d_in[2];
    const void* conv_b = d_in[3];
    const void* W_x    = d_in[4];
    const void* W_dt   = d_in[5];
    const void* b_dt   = d_in[6];
    const void* A_log  = d_in[7];
    const void* Dv     = d_in[8];
    const void* W_out  = d_in[9];

    char* ws = (char*)d_ws;
    u16*   xz     = (u16*)(ws);               // 8388608 B
    u16*   xconv  = (u16*)(ws + 8388608);     // 4194304 B
    float* xdbl   = (float*)(ws + 12582912);  // 393216 B
    u16*   dtb    = (u16*)(ws + 12976128);    // 131072 B
    float* delta  = (float*)(ws + 13107200);  // 8388608 B
    u16*   W_in_t = (u16*)(ws + 13107200);    // alias: W_in^T [4096,1024], GEMM1 only
    u16*   yg     = (u16*)(ws + 21495808);    // 4194304 B
    u16*   xb     = (u16*)(ws + 21495808);    // alias: x bf16, GEMM1 only
    u16*   W_x_b  = (u16*)(ws + 25690112);    // 393216 B
    u16*   W_dt_b = (u16*)(ws + 26083328);    // 262144 B
    u16*   W_out_t= (u16*)(ws + 26345472);    // W_out^T [1024,2048] bf16 = 4194304 B
    int*   flag   = (int*)(ws + 30539776);    // 4 B
    float* Acar   = (float*)(ws + 30539904);  // C*131072 B (Bcar follows)

    int C = 0;
    const size_t carry_base = 30539904;
    if (carry_base + (size_t)2 * 32 * 131072 <= ws_size) C = 32;
    else if (carry_base + (size_t)2 * 16 * 131072 <= ws_size) C = 16;
    else if (carry_base + (size_t)2 * 8 * 131072 <= ws_size) C = 8;
    float* Bcar = (C > 0) ? (float*)(ws + carry_base + (size_t)C * 131072) : nullptr;

    // 0) dtype detect; canonicalize x/W_x/W_dt; transpose-convert W_in, W_out
    detect_k<<<1, 256, 0, stream>>>((const u16*)x, flag);
    cvtall_k<<<5376, 256, 0, stream>>>(x, W_x, W_dt, xb, W_x_b, W_dt_b, flag);
    tcvt_k<<<dim3(32, 128), 256, 0, stream>>>(W_in, W_in_t, 1024, 4096, flag);
    tcvt_k<<<dim3(64, 32), 256, 0, stream>>>(W_out, W_out_t, 2048, 1024, flag);

    // 1) xz = x @ W_in   [1024,4096] bf16  (128x128 tiles, 256 blocks)
    gemm_bt<4, 4, 1><<<dim3(8, 32), 256, 0, stream>>>(xb, W_in_t, (void*)xz,
                                                      1024, 4096, 1024, flag);
    // 2) x_conv = silu(causal_dw_conv(x_in))
    conv_silu_k<<<8192, 256, 0, stream>>>(xz, conv_w, conv_b, xconv, flag);
    // 3) x_dbl = x_conv @ W_x   [1024,96] fp32 (+ dt cols -> bf16 dtb)
    gemm_k<3><<<dim3(16, 2), 256, 0, stream>>>(xconv, W_x_b, (void*)xdbl, 1024, 96, 2048,
                                               flag, dtb, nullptr);
    // 4) delta = softplus(dt @ W_dt + b_dt)   [1024,2048] fp32 (fused epilogue)
    gemm_k<4><<<dim3(16, 32), 256, 0, stream>>>(dtb, W_dt_b, (void*)delta, 1024, 2048, 64,
                                                flag, nullptr, b_dt);

    // 5) selective scan + gating -> yg bf16
    if (C == 32) {
        scan1_k<32><<<512, 256, 0, stream>>>(delta, xconv, xdbl, A_log, Acar, Bcar, flag);
        scan2_k<<<128, 256, 0, stream>>>(Acar, Bcar, 32);
        scan3_k<32><<<512, 256, 0, stream>>>(delta, xconv, xdbl, xz, A_log, Dv, Bcar, yg, flag);
    } else if (C == 16) {
        scan1_k<64><<<256, 256, 0, stream>>>(delta, xconv, xdbl, A_log, Acar, Bcar, flag);
        scan2_k<<<128, 256, 0, stream>>>(Acar, Bcar, 16);
        scan3_k<64><<<256, 256, 0, stream>>>(delta, xconv, xdbl, xz, A_log, Dv, Bcar, yg, flag);
    } else if (C == 8) {
        scan1_k<128><<<128, 256, 0, stream>>>(delta, xconv, xdbl, A_log, Acar, Bcar, flag);
        scan2_k<<<128, 256, 0, stream>>>(Acar, Bcar, 8);
        scan3_k<128><<<128, 256, 0, stream>>>(delta, xconv, xdbl, xz, A_log, Dv, Bcar, yg, flag);
    } else {
        scan_k<<<128, 256, 0, stream>>>(delta, xconv, xdbl, xz, A_log, Dv, yg, flag);
    }

    // 6) out = yg @ W_out   [1024,1024], dtype per flag  (64x128 tiles, 128 blocks)
    gemm_bt<2, 4, 2><<<dim3(16, 8), 256, 0, stream>>>(yg, W_out_t, d_out,
                                                      1024, 1024, 2048, flag);
}

// Round 7
// 255.585 us; speedup vs baseline: 4.1664x; 1.0702x over previous
//
#include <hip/hip_runtime.h>

typedef unsigned short u16;
typedef unsigned int u32;
typedef __attribute__((ext_vector_type(8))) short bf16x8;
typedef __attribute__((ext_vector_type(4))) float f32x4;

#define LSEQ 1024

__device__ __forceinline__ float b2f(u16 v) { return __uint_as_float(((u32)v) << 16); }
__device__ __forceinline__ u16 f2b(float f) {
    u32 x = __float_as_uint(f);
    return (u16)((x + 0x7fffu + ((x >> 16) & 1u)) >> 16);
}
__device__ __forceinline__ float rdf(const void* p, size_t i, int f) {
    return f ? b2f(((const u16*)p)[i]) : ((const float*)p)[i];
}
__device__ __forceinline__ float fsig(float x) {
    return __builtin_amdgcn_rcpf(1.f + __expf(-x));
}

typedef const __attribute__((address_space(1))) u32* gp_t;
typedef __attribute__((address_space(3))) u32* lp_t;
// async global->LDS, 16B per lane; LDS dest = wave-uniform base + lane*16
__device__ __forceinline__ void gload16(const u16* g, u16* lds_wave_base) {
    __builtin_amdgcn_global_load_lds((gp_t)g, (lp_t)lds_wave_base, 16, 0, 0);
}

// ---------------- dtype detection ----------------
__global__ void detect_k(const u16* __restrict__ x, int* __restrict__ flag) {
    __shared__ int cnt;
    if (threadIdx.x == 0) cnt = 0;
    __syncthreads();
    int c = 0;
#pragma unroll
    for (int j = 0; j < 8; ++j) {
        u16 u = x[threadIdx.x * 8 + j];
        int e = (u >> 7) & 0xFF;
        c += (e == 0 || (e >= 100 && e <= 140)) ? 1 : 0;
    }
    atomicAdd(&cnt, c);
    __syncthreads();
    if (threadIdx.x == 0) *flag = (cnt >= 1638) ? 1 : 0;
}

// ---------------- x -> bf16 ----------------
__global__ __launch_bounds__(256) void cvtx_k(const void* __restrict__ src,
                                              u16* __restrict__ dst,
                                              const int* __restrict__ flag) {
    int f = *flag;
    int i = blockIdx.x * 256 + threadIdx.x;  // over 1048576
    dst[i] = f ? ((const u16*)src)[i] : f2b(((const float*)src)[i]);
}

// ---------------- all weight transposes (+convert to bf16) in one kernel ----------------
// dst[Cp, R] = src[R, Cn]^T, rows >= Cn zero-padded. Tiles 32x32.
__global__ __launch_bounds__(256) void tall_k(const void* __restrict__ W_in,
                                              const void* __restrict__ W_out,
                                              const void* __restrict__ W_x,
                                              const void* __restrict__ W_dt,
                                              u16* __restrict__ W_in_t,
                                              u16* __restrict__ W_out_t,
                                              u16* __restrict__ W_x_t,
                                              u16* __restrict__ W_dt_t,
                                              const int* __restrict__ flag) {
    int f = *flag;
    __shared__ u16 tile[32][33];
    int blk = blockIdx.x;
    const void* src; u16* dst; int R, Cn, nbc, t;
    if (blk < 4096)      { src = W_in;  dst = W_in_t;  R = 1024; Cn = 4096; nbc = 128; t = blk; }
    else if (blk < 6144) { src = W_out; dst = W_out_t; R = 2048; Cn = 1024; nbc = 32;  t = blk - 4096; }
    else if (blk < 6400) { src = W_x;   dst = W_x_t;   R = 2048; Cn = 96;   nbc = 4;   t = blk - 6144; }
    else                 { src = W_dt;  dst = W_dt_t;  R = 64;   Cn = 2048; nbc = 64;  t = blk - 6400; }
    int br = t / nbc, bc = t - br * nbc;
    int r0 = br * 32, c0 = bc * 32;
    int tx = threadIdx.x & 31, ty0 = threadIdx.x >> 5;
#pragma unroll
    for (int p = 0; p < 4; ++p) {
        int ty = ty0 + p * 8;
        float v = (c0 + tx < Cn) ? rdf(src, (size_t)(r0 + ty) * Cn + c0 + tx, f) : 0.f;
        tile[ty][tx] = f2b(v);
    }
    __syncthreads();
#pragma unroll
    for (int p = 0; p < 4; ++p) {
        int ty = ty0 + p * 8;
        dst[(size_t)(c0 + ty) * R + r0 + tx] = tile[tx][ty];
    }
}

// ---------------- GEMM, B transposed: C[M,N] = A[M,K] * Bt[N,K]^T ----------------
// 256 threads = 4 waves in 2x2; wave-tile 16*MT x 16*NT; block 32*MT x 32*NT.
// global_load_lds width-16 staging into stride-32 LDS; ds_read_b128 fragments.
// OUT_MODE: 1=bf16, 2=dual(flag), 4=softplus(v+bias[col]) fp32,
//           5=fp32 partial at C + blockIdx.z*M*N (K split into kslices)
template <int MT, int NT, int OUT_MODE>
__global__ __launch_bounds__(256) void gemm_bt(const u16* __restrict__ A,
                                               const u16* __restrict__ Bt,
                                               void* __restrict__ C,
                                               int M, int N, int K,
                                               const int* __restrict__ flag,
                                               const void* __restrict__ bias,
                                               int kslices) {
    constexpr int BM = 32 * MT, BN = 32 * NT;
    __shared__ __align__(16) u16 As[BM * 32];
    __shared__ __align__(16) u16 Bs[BN * 32];
    const int tid = threadIdx.x;
    const int w = tid >> 6, lane = tid & 63;
    const int wm = w & 1, wn = w >> 1;
    const int m_blk = blockIdx.x * BM, n_blk = blockIdx.y * BN;
    const int lm = lane & 15, lq = lane >> 4;
    const int sr = lane >> 2, sc = (lane & 3) << 3;
    const int f = (OUT_MODE == 2 || OUT_MODE == 4) ? flag[0] : 0;
    const int klen = K / kslices;
    const int kb0 = blockIdx.z * klen;

    f32x4 acc[MT][NT];
#pragma unroll
    for (int i = 0; i < MT; ++i)
#pragma unroll
        for (int j = 0; j < NT; ++j) acc[i][j] = (f32x4){0.f, 0.f, 0.f, 0.f};

    for (int kb = kb0; kb < kb0 + klen; kb += 32) {
        __syncthreads();
#pragma unroll
        for (int i = 0; i < BM / 64; ++i) {
            int row = i * 64 + w * 16;
            gload16(A + (size_t)(m_blk + row + sr) * K + kb + sc, As + row * 32);
        }
#pragma unroll
        for (int i = 0; i < BN / 64; ++i) {
            int row = i * 64 + w * 16;
            gload16(Bt + (size_t)(n_blk + row + sr) * K + kb + sc, Bs + row * 32);
        }
        __syncthreads();

        bf16x8 af[MT], bf[NT];
#pragma unroll
        for (int tm = 0; tm < MT; ++tm)
            af[tm] = *(const bf16x8*)(As + (wm * 16 * MT + tm * 16 + lm) * 32 + lq * 8);
#pragma unroll
        for (int tn = 0; tn < NT; ++tn)
            bf[tn] = *(const bf16x8*)(Bs + (wn * 16 * NT + tn * 16 + lm) * 32 + lq * 8);
#pragma unroll
        for (int tm = 0; tm < MT; ++tm)
#pragma unroll
            for (int tn = 0; tn < NT; ++tn)
                acc[tm][tn] = __builtin_amdgcn_mfma_f32_16x16x32_bf16(af[tm], bf[tn],
                                                                      acc[tm][tn], 0, 0, 0);
    }

#pragma unroll
    for (int tm = 0; tm < MT; ++tm)
#pragma unroll
        for (int tn = 0; tn < NT; ++tn)
#pragma unroll
            for (int r = 0; r < 4; ++r) {
                int row = m_blk + wm * 16 * MT + tm * 16 + lq * 4 + r;
                int col = n_blk + wn * 16 * NT + tn * 16 + lm;
                float v = acc[tm][tn][r];
                if (OUT_MODE == 1) {
                    ((u16*)C)[(size_t)row * N + col] = f2b(v);
                } else if (OUT_MODE == 2) {
                    if (f) ((u16*)C)[(size_t)row * N + col] = f2b(v);
                    else   ((float*)C)[(size_t)row * N + col] = v;
                } else if (OUT_MODE == 4) {
                    float b = rdf(bias, col, f);
                    float t2 = v + b;
                    float sp = fmaxf(t2, 0.f) + __logf(1.f + __expf(-fabsf(t2)));
                    ((float*)C)[(size_t)row * N + col] = sp;
                } else {  // 5: fp32 partial per k-slice
                    ((float*)C)[(size_t)blockIdx.z * M * N + (size_t)row * N + col] = v;
                }
            }
}

// ---------------- reduce 4 k-slice partials -> xdbl fp32 (+ dtb bf16) ----------------
__global__ __launch_bounds__(256) void reduce_k(const float* __restrict__ parts,
                                                float* __restrict__ xdbl,
                                                u16* __restrict__ dtb) {
    int idx = blockIdx.x * 256 + threadIdx.x;  // over 1024*128
    float s = parts[idx] + parts[131072 + idx] + parts[262144 + idx] + parts[393216 + idx];
    xdbl[idx] = s;
    int col = idx & 127;
    if (col < 64) dtb[(idx >> 7) * 64 + col] = f2b(s);
}

// ---------------- causal depthwise conv (K=4) + SiLU ----------------
__global__ __launch_bounds__(256) void conv_silu_k(const u16* __restrict__ xz,
                                                   const void* __restrict__ cw,
                                                   const void* __restrict__ cb,
                                                   u16* __restrict__ xc,
                                                   const int* __restrict__ flag) {
    int f = *flag;
    int idx = blockIdx.x * 256 + threadIdx.x;  // over 1024*2048
    int t = idx >> 11, d = idx & 2047;
    float acc = rdf(cb, d, f);
#pragma unroll
    for (int k = 0; k < 4; ++k) {
        int tt = t + k - 3;
        if (tt >= 0) acc += b2f(xz[(size_t)tt * 4096 + d]) * rdf(cw, d * 4 + k, f);
    }
    xc[idx] = f2b(acc * fsig(acc));
}

// ---------------- chunked selective scan, (d, n-half) per lane; xdbl stride 128 ----------------
template <int T>
__global__ __launch_bounds__(256) void scan1_k(const float* __restrict__ delta,
                                               const u16* __restrict__ xc,
                                               const float* __restrict__ xdbl,
                                               const void* __restrict__ A_log,
                                               float* __restrict__ Acar,
                                               float* __restrict__ Bcar,
                                               const int* __restrict__ flag) {
    int f = *flag;
    int g = blockIdx.x * 256 + threadIdx.x;  // over C*4096
    int c = g >> 12, rem = g & 4095;
    int d = rem >> 1, nh = rem & 1;
    int n0 = nh << 3;
    float A[8], P[8], h[8];
#pragma unroll
    for (int j = 0; j < 8; ++j) {
        A[j] = -__expf(rdf(A_log, d * 16 + n0 + j, f));
        P[j] = 1.f;
        h[j] = 0.f;
    }
    int t0 = c * T;
#pragma unroll 4
    for (int i = 0; i < T; ++i) {
        int t = t0 + i;
        float de = delta[t * 2048 + d];
        float dBu = de * b2f(xc[t * 2048 + d]);
        f32x4 Bv0 = *(const f32x4*)(xdbl + t * 128 + 64 + n0);
        f32x4 Bv1 = *(const f32x4*)(xdbl + t * 128 + 68 + n0);
#pragma unroll
        for (int j = 0; j < 8; ++j) {
            float Bv = (j < 4) ? Bv0[j & 3] : Bv1[j & 3];
            float a = __expf(de * A[j]);
            h[j] = a * h[j] + Bv * dBu;
            P[j] *= a;
        }
    }
    f32x4 pa0 = {P[0], P[1], P[2], P[3]}, pa1 = {P[4], P[5], P[6], P[7]};
    f32x4 hb0 = {h[0], h[1], h[2], h[3]}, hb1 = {h[4], h[5], h[6], h[7]};
    size_t base = (size_t)c * 32768 + d * 16 + n0;
    *(f32x4*)(Acar + base) = pa0;
    *(f32x4*)(Acar + base + 4) = pa1;
    *(f32x4*)(Bcar + base) = hb0;
    *(f32x4*)(Bcar + base + 4) = hb1;
}

__global__ __launch_bounds__(256) void scan2_k(const float* __restrict__ Acar,
                                               float* __restrict__ Bcar, int C) {
    int idx = blockIdx.x * 256 + threadIdx.x;  // over 32768
    float H = 0.f;
    for (int c = 0; c < C; ++c) {
        float a = Acar[c * 32768 + idx];
        float b = Bcar[c * 32768 + idx];
        Bcar[c * 32768 + idx] = H;
        H = a * H + b;
    }
}

template <int T>
__global__ __launch_bounds__(256) void scan3_k(const float* __restrict__ delta,
                                               const u16* __restrict__ xc,
                                               const float* __restrict__ xdbl,
                                               const u16* __restrict__ xz,
                                               const void* __restrict__ A_log,
                                               const void* __restrict__ Dvp,
                                               const float* __restrict__ Bcar,
                                               u16* __restrict__ yg,
                                               const int* __restrict__ flag) {
    int f = *flag;
    int g = blockIdx.x * 256 + threadIdx.x;  // over C*4096
    int c = g >> 12, rem = g & 4095;
    int d = rem >> 1, nh = rem & 1;
    int n0 = nh << 3;
    float A[8], h[8];
    size_t base = (size_t)c * 32768 + d * 16 + n0;
    f32x4 h0 = *(const f32x4*)(Bcar + base);
    f32x4 h1 = *(const f32x4*)(Bcar + base + 4);
#pragma unroll
    for (int j = 0; j < 8; ++j) {
        A[j] = -__expf(rdf(A_log, d * 16 + n0 + j, f));
        h[j] = (j < 4) ? h0[j & 3] : h1[j & 3];
    }
    float Dd = rdf(Dvp, d, f);
    int t0 = c * T;
#pragma unroll 4
    for (int i = 0; i < T; ++i) {
        int t = t0 + i;
        float de = delta[t * 2048 + d];
        float u = b2f(xc[t * 2048 + d]);
        float dBu = de * u;
        f32x4 Bv0 = *(const f32x4*)(xdbl + t * 128 + 64 + n0);
        f32x4 Bv1 = *(const f32x4*)(xdbl + t * 128 + 68 + n0);
        f32x4 Cv0 = *(const f32x4*)(xdbl + t * 128 + 80 + n0);
        f32x4 Cv1 = *(const f32x4*)(xdbl + t * 128 + 84 + n0);
        float p = 0.f;
#pragma unroll
        for (int j = 0; j < 8; ++j) {
            float Bv = (j < 4) ? Bv0[j & 3] : Bv1[j & 3];
            float Cv = (j < 4) ? Cv0[j & 3] : Cv1[j & 3];
            float a = __expf(de * A[j]);
            h[j] = a * h[j] + Bv * dBu;
            p += h[j] * Cv;
        }
        p += __shfl_xor(p, 1);  // combine the two n-halves (lanes 2k,2k+1 share d)
        if (nh == 0) {
            float r = b2f(xz[(size_t)t * 4096 + 2048 + d]);
            float yt = p + u * Dd;
            yg[t * 2048 + d] = f2b(yt * r * fsig(r));
        }
    }
}

// fallback monolithic scan (only if ws too small for carries)
__global__ __launch_bounds__(256) void scan_k(const float* __restrict__ delta,
                                              const u16* __restrict__ xc,
                                              const float* __restrict__ xdbl,
                                              const u16* __restrict__ xz,
                                              const void* __restrict__ A_log,
                                              const void* __restrict__ Dvp,
                                              u16* __restrict__ yg,
                                              const int* __restrict__ flag) {
    int f = *flag;
    int g = blockIdx.x * 256 + threadIdx.x;
    int d = g >> 4, n = g & 15;
    float A = -__expf(rdf(A_log, d * 16 + n, f));
    float Dd = rdf(Dvp, d, f);
    float h = 0.f;
    for (int t = 0; t < LSEQ; ++t) {
        float de = delta[t * 2048 + d];
        float u = b2f(xc[t * 2048 + d]);
        float Bv = xdbl[t * 128 + 64 + n];
        float Cv = xdbl[t * 128 + 80 + n];
        h = __expf(de * A) * h + (de * Bv) * u;
        float p = h * Cv;
        p += __shfl_xor(p, 1);
        p += __shfl_xor(p, 2);
        p += __shfl_xor(p, 4);
        p += __shfl_xor(p, 8);
        if (n == 0) {
            float r = b2f(xz[(size_t)t * 4096 + 2048 + d]);
            float yt = p + u * Dd;
            yg[t * 2048 + d] = f2b(yt * r * fsig(r));
        }
    }
}

extern "C" void kernel_launch(void* const* d_in, const int* in_sizes, int n_in,
                              void* d_out, int out_size, void* d_ws, size_t ws_size,
                              hipStream_t stream) {
    const void* x      = d_in[0];
    const void* W_in   = d_in[1];
    const void* conv_w = d_in[2];
    const void* conv_b = d_in[3];
    const void* W_x    = d_in[4];
    const void* W_dt   = d_in[5];
    const void* b_dt   = d_in[6];
    const void* A_log  = d_in[7];
    const void* Dv     = d_in[8];
    const void* W_out  = d_in[9];

    char* ws = (char*)d_ws;
    u16*   xz     = (u16*)(ws);               // 8388608 B
    u16*   xconv  = (u16*)(ws + 8388608);     // 4194304 B
    float* xdbl   = (float*)(ws + 12582912);  // [1024,128] fp32 = 524288 B
    u16*   dtb    = (u16*)(ws + 13107200);    // [1024,64] bf16 = 131072 B
    float* parts  = (float*)(ws + 13238272);  // [4,1024,128] fp32 = 2097152 B
    float* delta  = (float*)(ws + 15335424);  // 8388608 B
    u16*   W_in_t = (u16*)(ws + 15335424);    // alias: W_in^T [4096,1024], gemm1 only
    u16*   yg     = (u16*)(ws + 23724032);    // 4194304 B
    u16*   xb     = (u16*)(ws + 23724032);    // alias: x bf16, gemm1 only
    u16*   W_x_t  = (u16*)(ws + 27918336);    // W_x^T padded [128,2048] = 524288 B
    u16*   W_dt_t = (u16*)(ws + 28442624);    // W_dt^T [2048,64] = 262144 B
    u16*   W_out_t= (u16*)(ws + 28704768);    // W_out^T [1024,2048] = 4194304 B
    int*   flag   = (int*)(ws + 32899072);    // 4 B
    float* Acar   = (float*)(ws + 32899200);  // C*131072 B (Bcar follows)

    int C = 0;
    const size_t carry_base = 32899200;
    if (carry_base + (size_t)2 * 32 * 131072 <= ws_size) C = 32;
    else if (carry_base + (size_t)2 * 16 * 131072 <= ws_size) C = 16;
    else if (carry_base + (size_t)2 * 8 * 131072 <= ws_size) C = 8;
    float* Bcar = (C > 0) ? (float*)(ws + carry_base + (size_t)C * 131072) : nullptr;

    // 0) dtype detect; x -> bf16; all 4 weight transposes (bf16) in one kernel
    detect_k<<<1, 256, 0, stream>>>((const u16*)x, flag);
    cvtx_k<<<4096, 256, 0, stream>>>(x, xb, flag);
    tall_k<<<6528, 256, 0, stream>>>(W_in, W_out, W_x, W_dt,
                                     W_in_t, W_out_t, W_x_t, W_dt_t, flag);

    // 1) xz = x @ W_in   [1024,4096] bf16  (64x128 tiles, 512 blocks)
    gemm_bt<2, 4, 1><<<dim3(16, 32), 256, 0, stream>>>(xb, W_in_t, (void*)xz,
                                                       1024, 4096, 1024, flag, nullptr, 1);
    // 2) x_conv = silu(causal_dw_conv(x_in))
    conv_silu_k<<<8192, 256, 0, stream>>>(xz, conv_w, conv_b, xconv, flag);
    // 3) x_dbl partials = x_conv @ W_x^T(padded 128)   K split 4 ways, 32 blocks
    gemm_bt<4, 4, 5><<<dim3(8, 1, 4), 256, 0, stream>>>(xconv, W_x_t, (void*)parts,
                                                        1024, 128, 2048, flag, nullptr, 4);
    // 3b) reduce partials -> xdbl fp32 (+ dtb bf16)
    reduce_k<<<512, 256, 0, stream>>>(parts, xdbl, dtb);
    // 4) delta = softplus(dt @ W_dt + b_dt)   [1024,2048] fp32 (fused epilogue)
    gemm_bt<4, 4, 4><<<dim3(8, 16), 256, 0, stream>>>(dtb, W_dt_t, (void*)delta,
                                                      1024, 2048, 64, flag, b_dt, 1);

    // 5) selective scan + gating -> yg bf16
    if (C == 32) {
        scan1_k<32><<<512, 256, 0, stream>>>(delta, xconv, xdbl, A_log, Acar, Bcar, flag);
        scan2_k<<<128, 256, 0, stream>>>(Acar, Bcar, 32);
        scan3_k<32><<<512, 256, 0, stream>>>(delta, xconv, xdbl, xz, A_log, Dv, Bcar, yg, flag);
    } else if (C == 16) {
        scan1_k<64><<<256, 256, 0, stream>>>(delta, xconv, xdbl, A_log, Acar, Bcar, flag);
        scan2_k<<<128, 256, 0, stream>>>(Acar, Bcar, 16);
        scan3_k<64><<<256, 256, 0, stream>>>(delta, xconv, xdbl, xz, A_log, Dv, Bcar, yg, flag);
    } else if (C == 8) {
        scan1_k<128><<<128, 256, 0, stream>>>(delta, xconv, xdbl, A_log, Acar, Bcar, flag);
        scan2_k<<<128, 256, 0, stream>>>(Acar, Bcar, 8);
        scan3_k<128><<<128, 256, 0, stream>>>(delta, xconv, xdbl, xz, A_log, Dv, Bcar, yg, flag);
    } else {
        scan_k<<<128, 256, 0, stream>>>(delta, xconv, xdbl, xz, A_log, Dv, yg, flag);
    }

    // 6) out = yg @ W_out   [1024,1024], dtype per flag  (64x128 tiles, 128 blocks)
    gemm_bt<2, 4, 2><<<dim3(16, 8), 256, 0, stream>>>(yg, W_out_t, d_out,
                                                      1024, 1024, 2048, flag, nullptr, 1);
}